// Round 13
// baseline (319.340 us; speedup 1.0000x reference)
//
#include <hip/hip_runtime.h>
#include <math.h>

#define NN 50000
#define HID 128
#define NG 64
#define BN_EPS 1e-5f

typedef __attribute__((ext_vector_type(8))) short short8;
typedef __attribute__((ext_vector_type(4))) float f32x4;

// ---- bf16 pack/unpack (RNE) ----
__device__ inline unsigned pack_bf2(float a, float b) {
    union { float f; unsigned u; } ua, ub;
    ua.f = a; ub.f = b;
    unsigned x = ua.u, y = ub.u;
    x += 0x7fffu + ((x >> 16) & 1u);
    y += 0x7fffu + ((y >> 16) & 1u);
    return (x >> 16) | (y & 0xffff0000u);
}
__device__ inline unsigned short bf16_1(float x) {
    union { float f; unsigned u; } v;
    v.f = x;
    unsigned r = v.u + 0x7fffu + ((v.u >> 16) & 1u);
    return (unsigned short)(r >> 16);
}
__device__ inline float2 unpack_bf2(unsigned v) {
    union { unsigned u; float f; } a, b;
    a.u = v << 16;
    b.u = v & 0xffff0000u;
    return make_float2(a.f, b.f);
}

// =============== bucketed CSR build — fixed-capacity buckets ===============
#define NBKT 256
#define ETILE 8192
#define CAP   8192

// tiny init: cursors + logits bias (must complete before k_distribute)
__global__ __launch_bounds__(256) void k_init(int* __restrict__ bcurP,
                                              const float* __restrict__ cls_b,
                                              float* __restrict__ logits) {
    int t = threadIdx.x;
    bcurP[t * 16] = t * CAP;
    if (t < NG) logits[t] = cls_b[0];
}

// blocks < etiles: scatter packed edges into bucket segments.
// blocks >= etiles: W transpose+bf16 (consumed only after next kernel boundary).
__global__ __launch_bounds__(256) void k_distribute(const int* __restrict__ src,
                                                    const int* __restrict__ dst,
                                                    int* __restrict__ bcurP,
                                                    unsigned* __restrict__ bpacked,
                                                    const float* __restrict__ W1,
                                                    const float* __restrict__ W2,
                                                    unsigned short* __restrict__ wt1,
                                                    unsigned short* __restrict__ wt2,
                                                    int etiles, int E, int K) {
    if ((int)blockIdx.x >= etiles) {
        int b2 = blockIdx.x - etiles;          // 0..255
        int k = b2 & 127;
        const float* W = (b2 < 128) ? W1 : W2;
        unsigned short* wt = (b2 < 128) ? wt1 : wt2;
        int c = threadIdx.x;
        if (c < 128) wt[c * 128 + k] = bf16_1(W[k * 128 + c]);
        return;
    }
    __shared__ int h[NBKT];
    int t = threadIdx.x;
    h[t] = 0;
    __syncthreads();
    int base = blockIdx.x * ETILE;
    for (int i = 0; i < ETILE / 256; ++i) {
        int e = base + i * 256 + t;
        if (e < E) atomicAdd(&h[dst[e] / K], 1);
    }
    __syncthreads();
    int c = h[t];
    int my = (c > 0) ? atomicAdd(&bcurP[t * 16], c) : 0;
    __syncthreads();
    h[t] = my;
    __syncthreads();
    for (int i = 0; i < ETILE / 256; ++i) {
        int e = base + i * 256 + t;
        if (e < E) {
            int d = dst[e];
            int p = atomicAdd(&h[d / K], 1);
            bpacked[p] = ((unsigned)d << 16) | (unsigned)src[e];
        }
    }
}

// one block per bucket: counting sort -> row_ptr/deg/dis/col_idx + degree-sorted perm
__global__ __launch_bounds__(256) void k_bucket_csr(const unsigned* __restrict__ bpacked,
                                                    const int* __restrict__ bcurP,
                                                    int* __restrict__ row_ptr,
                                                    int* __restrict__ degA,
                                                    float* __restrict__ dis,
                                                    int* __restrict__ col_idx,
                                                    int* __restrict__ perm,
                                                    int n, int K) {
    __shared__ int cnt[NBKT];
    __shared__ int sA[NBKT];
    __shared__ int cur[NBKT];
    int t = threadIdx.x;
    int b = blockIdx.x;
    int node0 = b * K;
    int nn = n - node0;
    if (nn > K) nn = K;
    if (nn < 0) nn = 0;
    int e0 = b * CAP;
    int e1 = bcurP[b * 16];
    cnt[t] = 0;
    __syncthreads();
    for (int e = e0 + t; e < e1; e += 256) {
        int ld = (int)(bpacked[e] >> 16) - node0;
        atomicAdd(&cnt[ld], 1);
    }
    __syncthreads();
    int c = cnt[t];
    sA[t] = c;
    __syncthreads();
    for (int off = 1; off < NBKT; off <<= 1) {
        int v = (t >= off) ? sA[t - off] : 0;
        __syncthreads();
        sA[t] += v;
        __syncthreads();
    }
    int rp = e0 + sA[t] - c;
    cur[t] = rp;
    if (t < nn) {
        row_ptr[node0 + t] = rp;
        degA[node0 + t] = c;
        dis[node0 + t] = rsqrtf((float)(c + 1));
    }
    __syncthreads();
    for (int e = e0 + t; e < e1; e += 256) {
        unsigned v = bpacked[e];
        int ld = (int)(v >> 16) - node0;
        int p = atomicAdd(&cur[ld], 1);
        col_idx[p] = (int)(v & 0xFFFFu);
    }
    // ---- bucket-local degree sort -> perm (reuse sA/cur as hist/scan) ----
    __syncthreads();
    sA[t] = 0;
    __syncthreads();
    int dc = (c > 255) ? 255 : c;
    if (t < nn) atomicAdd(&sA[dc], 1);
    __syncthreads();
    cur[t] = sA[t];
    __syncthreads();
    for (int off = 1; off < NBKT; off <<= 1) {
        int v = (t >= off) ? cur[t - off] : 0;
        __syncthreads();
        cur[t] += v;
        __syncthreads();
    }
    int dbase = cur[t] - sA[t];        // exclusive base of degree bin t
    __syncthreads();
    sA[t] = dbase;                     // sA becomes per-bin cursor
    __syncthreads();
    if (t < nn) {
        int r = atomicAdd(&sA[dc], 1);
        perm[node0 + r] = node0 + t;
    }
}

// =============== MFMA GEMM: outb = bf16( dis[row] * (in @ W) ) ===============

#define ASTR 136

__global__ __launch_bounds__(256) void k_gemm_mfma(const void* __restrict__ inp,
                                                   const unsigned short* __restrict__ wt,
                                                   const float* __restrict__ dis,
                                                   unsigned short* __restrict__ outb,
                                                   int n, int fmt) {
    __shared__ unsigned short A[64][ASTR];
    int t = threadIdx.x;
    int row0 = blockIdx.x * 64;

    if (fmt == 0) {          // f32 input
        const float* in = (const float*)inp;
        #pragma unroll
        for (int i = 0; i < 8; ++i) {
            int idx = t + i * 256;
            int r = idx >> 5;
            int c4 = (idx & 31) * 4;
            float4 v = make_float4(0.f, 0.f, 0.f, 0.f);
            if (row0 + r < n) v = *(const float4*)&in[(size_t)(row0 + r) * 128 + c4];
            uint2 p;
            p.x = pack_bf2(v.x, v.y);
            p.y = pack_bf2(v.z, v.w);
            *(uint2*)&A[r][c4] = p;
        }
    } else {                 // bf16 input
        const unsigned short* in = (const unsigned short*)inp;
        #pragma unroll
        for (int i = 0; i < 4; ++i) {
            int idx = t + i * 256;
            int r = idx >> 4;
            int c8 = (idx & 15) * 8;
            uint4 v = make_uint4(0, 0, 0, 0);
            if (row0 + r < n) v = *(const uint4*)&in[(size_t)(row0 + r) * 128 + c8];
            *(uint4*)&A[r][c8] = v;
        }
    }
    __syncthreads();

    int lane = t & 63;
    int wave = t >> 6;
    int m = lane & 15;
    int quad = lane >> 4;
    int r0 = wave * 16;

    short8 a[4];
    #pragma unroll
    for (int kt = 0; kt < 4; ++kt)
        a[kt] = *(const short8*)&A[r0 + m][kt * 32 + quad * 8];

    f32x4 acc[8];
    #pragma unroll
    for (int ct = 0; ct < 8; ++ct) acc[ct] = (f32x4){0.f, 0.f, 0.f, 0.f};

    // B-frag double-buffer: prefetch ct+1 while MFMAs consume ct
    short8 bcur[4], bnxt[4];
    {
        const unsigned short* wb = &wt[(size_t)m * 128 + quad * 8];
        #pragma unroll
        for (int kt = 0; kt < 4; ++kt) bcur[kt] = *(const short8*)(wb + kt * 32);
    }
    #pragma unroll
    for (int ct = 0; ct < 8; ++ct) {
        if (ct < 7) {
            const unsigned short* wb = &wt[(size_t)((ct + 1) * 16 + m) * 128 + quad * 8];
            #pragma unroll
            for (int kt = 0; kt < 4; ++kt) bnxt[kt] = *(const short8*)(wb + kt * 32);
        }
        #pragma unroll
        for (int kt = 0; kt < 4; ++kt)
            acc[ct] = __builtin_amdgcn_mfma_f32_16x16x32_bf16(a[kt], bcur[kt], acc[ct], 0, 0, 0);
        #pragma unroll
        for (int kt = 0; kt < 4; ++kt) bcur[kt] = bnxt[kt];
    }

    int gr = row0 + r0 + quad * 4;
    float ds[4];
    #pragma unroll
    for (int reg = 0; reg < 4; ++reg)
        ds[reg] = (gr + reg < n) ? dis[gr + reg] : 0.f;

    __syncthreads();
    #pragma unroll
    for (int ct = 0; ct < 8; ++ct) {
        int col = ct * 16 + m;
        #pragma unroll
        for (int reg = 0; reg < 4; ++reg)
            A[r0 + quad * 4 + reg][col] = bf16_1(acc[ct][reg] * ds[reg]);
    }
    __syncthreads();
    #pragma unroll
    for (int i = 0; i < 4; ++i) {
        int idx = t + i * 256;
        int r = idx >> 4;
        int c8 = (idx & 15) * 8;
        int grow = row0 + r;
        if (grow < n)
            *(uint4*)&outb[(size_t)grow * 128 + c8] = *(const uint4*)&A[r][c8];
    }
}

// =============== agg core: 16 lanes/node, 16 uint4 in flight, col_idx pipelined ===========

__device__ inline void gather4wide(const unsigned short* __restrict__ hwsb,
                                   const int* __restrict__ col_idx,
                                   int e0, int deg, int md,
                                   int sl, int part, bool active,
                                   float* acc8) {
    int cidx = (active && sl < deg) ? col_idx[e0 + sl] : 0;
    for (int it0 = 0; it0 < md; it0 += 16) {
        int nx = it0 + 16;
        int cidx_next = (active && (nx + sl) < deg && nx < md) ? col_idx[e0 + nx + sl] : 0;
        uint4 vv[16];
        #pragma unroll
        for (int j = 0; j < 16; ++j) {
            int s = __shfl(cidx, (part << 4) + j);
            vv[j] = (it0 + j < deg)
                        ? *(const uint4*)(hwsb + ((size_t)s << 7) + (sl << 3))
                        : make_uint4(0, 0, 0, 0);
        }
        #pragma unroll
        for (int j = 0; j < 16; ++j) {
            const unsigned* w = (const unsigned*)&vv[j];
            #pragma unroll
            for (int i2 = 0; i2 < 4; ++i2) {
                float2 f = unpack_bf2(w[i2]);
                acc8[2 * i2]     += f.x;
                acc8[2 * i2 + 1] += f.y;
            }
        }
        cidx = cidx_next;
    }
}

// ------- layer-1 aggregation + bias + BN + ReLU -> h1 (bf16); perm-ordered -------

__global__ __launch_bounds__(256) void k_agg_bn_relu(const unsigned short* __restrict__ hwsb,
                                                     const int* __restrict__ row_ptr,
                                                     const int* __restrict__ degA,
                                                     const int* __restrict__ col_idx,
                                                     const int* __restrict__ perm,
                                                     const float* __restrict__ dis,
                                                     const float* __restrict__ bias,
                                                     const float* __restrict__ gamma,
                                                     const float* __restrict__ beta,
                                                     const float* __restrict__ mean,
                                                     const float* __restrict__ var,
                                                     unsigned short* __restrict__ outh, int n) {
    int t = threadIdx.x;
    int wave = t >> 6, lane = t & 63;
    int sl = lane & 15, part = lane >> 4;
    int slot = blockIdx.x * 16 + wave * 4 + part;
    bool active = (slot < n);
    int d = 0, e0 = 0, deg = 0;
    if (active) {
        d = perm[slot];
        e0 = row_ptr[d];
        deg = degA[d];
    }
    int md = deg;
    md = max(md, __shfl_xor(md, 16));
    md = max(md, __shfl_xor(md, 32));

    float acc8[8] = {0, 0, 0, 0, 0, 0, 0, 0};
    gather4wide(hwsb, col_idx, e0, deg, md, sl, part, active, acc8);
    if (!active) return;

    {   // self
        uint4 v = *(const uint4*)(hwsb + ((size_t)d << 7) + (sl << 3));
        const unsigned* w = (const unsigned*)&v;
        #pragma unroll
        for (int i2 = 0; i2 < 4; ++i2) {
            float2 f = unpack_bf2(w[i2]);
            acc8[2 * i2]     += f.x;
            acc8[2 * i2 + 1] += f.y;
        }
    }
    float dd = dis[d];
    int f0 = sl << 3;
    unsigned outw[4];
    #pragma unroll
    for (int i2 = 0; i2 < 4; ++i2) {
        int f = f0 + 2 * i2;
        float2 bv = *(const float2*)&bias[f];
        float2 gm = *(const float2*)&gamma[f];
        float2 bt = *(const float2*)&beta[f];
        float2 mn = *(const float2*)&mean[f];
        float2 vr = *(const float2*)&var[f];
        float vx = acc8[2 * i2] * dd + bv.x;
        float vy = acc8[2 * i2 + 1] * dd + bv.y;
        float sx = gm.x * rsqrtf(vr.x + BN_EPS);
        float sy = gm.y * rsqrtf(vr.y + BN_EPS);
        float rx = fmaxf((vx - mn.x) * sx + bt.x, 0.f);
        float ry = fmaxf((vy - mn.y) * sy + bt.y, 0.f);
        outw[i2] = pack_bf2(rx, ry);
    }
    *(uint4*)(outh + ((size_t)d << 7) + (sl << 3)) = *(uint4*)outw;
}

// ------- layer-2 agg + BN + ReLU + attention + logits; perm-ordered -------

__global__ __launch_bounds__(256) void k_agg2_att_logit(const unsigned short* __restrict__ hwsb,
                                                        const int* __restrict__ row_ptr,
                                                        const int* __restrict__ degA,
                                                        const int* __restrict__ col_idx,
                                                        const int* __restrict__ perm,
                                                        const float* __restrict__ dis,
                                                        const float* __restrict__ bias,
                                                        const float* __restrict__ gamma,
                                                        const float* __restrict__ beta,
                                                        const float* __restrict__ mean,
                                                        const float* __restrict__ var,
                                                        const int* __restrict__ batch,
                                                        const float* __restrict__ att_w,
                                                        const float* __restrict__ cls_w,
                                                        float* __restrict__ att_out,
                                                        float* __restrict__ logits, int n) {
    __shared__ int   sg[16];
    __shared__ float sv[16];
    int t = threadIdx.x;
    int wave = t >> 6, lane = t & 63;
    int sl = lane & 15, part = lane >> 4;
    int slot = blockIdx.x * 16 + wave * 4 + part;
    bool active = (slot < n);
    int d = 0, e0 = 0, deg = 0;
    if (active) {
        d = perm[slot];
        e0 = row_ptr[d];
        deg = degA[d];
    }
    int md = deg;
    md = max(md, __shfl_xor(md, 16));
    md = max(md, __shfl_xor(md, 32));

    float acc8[8] = {0, 0, 0, 0, 0, 0, 0, 0};
    gather4wide(hwsb, col_idx, e0, deg, md, sl, part, active, acc8);

    int g = -1;
    float contrib = 0.f;
    float p = 0.f, q = 0.f;
    if (active) {
        uint4 v = *(const uint4*)(hwsb + ((size_t)d << 7) + (sl << 3));
        const unsigned* w = (const unsigned*)&v;
        #pragma unroll
        for (int i2 = 0; i2 < 4; ++i2) {
            float2 f = unpack_bf2(w[i2]);
            acc8[2 * i2]     += f.x;
            acc8[2 * i2 + 1] += f.y;
        }
        float dd = dis[d];
        int f0 = sl << 3;
        #pragma unroll
        for (int i2 = 0; i2 < 4; ++i2) {
            int f = f0 + 2 * i2;
            float2 bv = *(const float2*)&bias[f];
            float2 gm = *(const float2*)&gamma[f];
            float2 bt = *(const float2*)&beta[f];
            float2 mn = *(const float2*)&mean[f];
            float2 vr = *(const float2*)&var[f];
            float vx = acc8[2 * i2] * dd + bv.x;
            float vy = acc8[2 * i2 + 1] * dd + bv.y;
            float sx = gm.x * rsqrtf(vr.x + BN_EPS);
            float sy = gm.y * rsqrtf(vr.y + BN_EPS);
            float rx = fmaxf((vx - mn.x) * sx + bt.x, 0.f);
            float ry = fmaxf((vy - mn.y) * sy + bt.y, 0.f);
            float2 aw = *(const float2*)&att_w[f];
            float2 cw = *(const float2*)&cls_w[f];
            p += rx * aw.x + ry * aw.y;
            q += rx * cw.x + ry * cw.y;
        }
    }
    #pragma unroll
    for (int off = 1; off < 16; off <<= 1) {
        p += __shfl_xor(p, off);
        q += __shfl_xor(q, off);
    }
    if (active) {
        float a = 1.f / (1.f + expf(-p));
        if (sl == 0) att_out[d] = a;
        g = batch[d];
        contrib = a * q;
    }
    if (sl == 0) {
        sg[wave * 4 + part] = g;
        sv[wave * 4 + part] = contrib;
    }
    __syncthreads();
    if (t == 0) {
        int cur = -1;
        float acc = 0.f;
        #pragma unroll
        for (int i = 0; i < 16; ++i) {
            int gi = sg[i];
            if (gi < 0) continue;
            if (gi != cur) {
                if (cur >= 0) atomicAdd(&logits[cur], acc);
                cur = gi;
                acc = 0.f;
            }
            acc += sv[i];
        }
        if (cur >= 0) atomicAdd(&logits[cur], acc);
    }
}

// ---------------- launch ----------------

extern "C" void kernel_launch(void* const* d_in, const int* in_sizes, int n_in,
                              void* d_out, int out_size, void* d_ws, size_t ws_size,
                              hipStream_t stream) {
    const float* x   = (const float*)d_in[0];
    const int*   ei  = (const int*)d_in[1];
    const int*   bat = (const int*)d_in[2];
    const float* W1  = (const float*)d_in[3];
    const float* b1  = (const float*)d_in[4];
    const float* g1  = (const float*)d_in[5];
    const float* bt1 = (const float*)d_in[6];
    const float* mn1 = (const float*)d_in[7];
    const float* vr1 = (const float*)d_in[8];
    const float* W2  = (const float*)d_in[9];
    const float* b2  = (const float*)d_in[10];
    const float* g2  = (const float*)d_in[11];
    const float* bt2 = (const float*)d_in[12];
    const float* mn2 = (const float*)d_in[13];
    const float* vr2 = (const float*)d_in[14];
    const float* attw = (const float*)d_in[15];
    const float* clsw = (const float*)d_in[16];
    const float* clsb = (const float*)d_in[17];

    int E = in_sizes[1] / 2;
    int n = in_sizes[2];
    const int* src = ei;
    const int* dst = ei + E;
    int K = (n + NBKT - 1) / NBKT;

    char* ws = (char*)d_ws;
    auto alloc = [&](size_t bytes) {
        void* p = (void*)ws;
        ws += (bytes + 255) & ~(size_t)255;
        return p;
    };
    int*            bcurP   = (int*)alloc(NBKT * 16 * 4);
    unsigned*       bpacked = (unsigned*)alloc((size_t)NBKT * CAP * 4);
    int*            row_ptr = (int*)alloc((size_t)n * 4);
    int*            degA    = (int*)alloc((size_t)n * 4);
    int*            col_idx = (int*)alloc((size_t)NBKT * CAP * 4);
    int*            perm    = (int*)alloc((size_t)n * 4);
    float*          dis     = (float*)alloc((size_t)n * 4);
    unsigned short* hwsb    = (unsigned short*)alloc((size_t)n * 128 * 2);
    unsigned short* h1b     = (unsigned short*)alloc((size_t)n * 128 * 2);
    unsigned short* wt1     = (unsigned short*)alloc(128 * 128 * 2);
    unsigned short* wt2     = (unsigned short*)alloc(128 * 128 * 2);

    float* out = (float*)d_out;
    int etiles = (E + ETILE - 1) / ETILE;
    int gb = (n + 63) / 64;
    int ab = (n + 15) / 16;

    k_init<<<1, 256, 0, stream>>>(bcurP, clsb, out);
    k_distribute<<<etiles + 256, 256, 0, stream>>>(src, dst, bcurP, bpacked,
                                                   W1, W2, wt1, wt2, etiles, E, K);
    k_bucket_csr<<<NBKT, 256, 0, stream>>>(bpacked, bcurP, row_ptr, degA, dis,
                                           col_idx, perm, n, K);

    k_gemm_mfma<<<gb, 256, 0, stream>>>(x, wt1, dis, hwsb, n, 0);
    k_agg_bn_relu<<<ab, 256, 0, stream>>>(hwsb, row_ptr, degA, col_idx, perm, dis,
                                          b1, g1, bt1, mn1, vr1, h1b, n);
    k_gemm_mfma<<<gb, 256, 0, stream>>>(h1b, wt2, dis, hwsb, n, 1);
    k_agg2_att_logit<<<ab, 256, 0, stream>>>(hwsb, row_ptr, degA, col_idx, perm, dis,
                                             b2, g2, bt2, mn2, vr2, bat, attw, clsw,
                                             out + NG, out, n);
}

// Round 14
// 309.000 us; speedup vs baseline: 1.0335x; 1.0335x over previous
//
#include <hip/hip_runtime.h>
#include <math.h>

#define NN 50000
#define HID 128
#define NG 64
#define BN_EPS 1e-5f

typedef __attribute__((ext_vector_type(8))) short short8;
typedef __attribute__((ext_vector_type(4))) float f32x4;

// ---- bf16 pack/unpack (RNE) ----
__device__ inline unsigned pack_bf2(float a, float b) {
    union { float f; unsigned u; } ua, ub;
    ua.f = a; ub.f = b;
    unsigned x = ua.u, y = ub.u;
    x += 0x7fffu + ((x >> 16) & 1u);
    y += 0x7fffu + ((y >> 16) & 1u);
    return (x >> 16) | (y & 0xffff0000u);
}
__device__ inline unsigned short bf16_1(float x) {
    union { float f; unsigned u; } v;
    v.f = x;
    unsigned r = v.u + 0x7fffu + ((v.u >> 16) & 1u);
    return (unsigned short)(r >> 16);
}
__device__ inline float2 unpack_bf2(unsigned v) {
    union { unsigned u; float f; } a, b;
    a.u = v << 16;
    b.u = v & 0xffff0000u;
    return make_float2(a.f, b.f);
}

// =============== bucketed CSR build — fixed-capacity buckets ===============
// bcurP holds RELATIVE cursors (zeroed by hipMemsetAsync); segment b = [b*CAP, ...).
#define NBKT 256
#define ETILE 8192
#define CAP   8192

// blocks < etiles: scatter packed edges into bucket segments.
// blocks >= etiles: W transpose+bf16 (consumed only after next kernel boundary).
__global__ __launch_bounds__(256) void k_distribute(const int* __restrict__ src,
                                                    const int* __restrict__ dst,
                                                    int* __restrict__ bcurP,
                                                    unsigned* __restrict__ bpacked,
                                                    const float* __restrict__ W1,
                                                    const float* __restrict__ W2,
                                                    unsigned short* __restrict__ wt1,
                                                    unsigned short* __restrict__ wt2,
                                                    int etiles, int E, int K) {
    if ((int)blockIdx.x >= etiles) {
        int b2 = blockIdx.x - etiles;          // 0..255
        int k = b2 & 127;
        const float* W = (b2 < 128) ? W1 : W2;
        unsigned short* wt = (b2 < 128) ? wt1 : wt2;
        int c = threadIdx.x;
        if (c < 128) wt[c * 128 + k] = bf16_1(W[k * 128 + c]);
        return;
    }
    __shared__ int h[NBKT];
    int t = threadIdx.x;
    h[t] = 0;
    __syncthreads();
    int base = blockIdx.x * ETILE;
    for (int i = 0; i < ETILE / 256; ++i) {
        int e = base + i * 256 + t;
        if (e < E) atomicAdd(&h[dst[e] / K], 1);
    }
    __syncthreads();
    int c = h[t];
    int my = (c > 0) ? atomicAdd(&bcurP[t * 16], c) : 0;   // relative base
    __syncthreads();
    h[t] = my;
    __syncthreads();
    for (int i = 0; i < ETILE / 256; ++i) {
        int e = base + i * 256 + t;
        if (e < E) {
            int d = dst[e];
            int bkt = d / K;
            int p = atomicAdd(&h[bkt], 1);
            bpacked[(size_t)bkt * CAP + p] = ((unsigned)d << 16) | (unsigned)src[e];
        }
    }
}

// one block per bucket: LDS counting sort -> row_ptr/deg/dis + col_idx.
// block 0 also seeds logits with cls_b.
__global__ __launch_bounds__(256) void k_bucket_csr(const unsigned* __restrict__ bpacked,
                                                    const int* __restrict__ bcurP,
                                                    int* __restrict__ row_ptr,
                                                    int* __restrict__ degA,
                                                    float* __restrict__ dis,
                                                    int* __restrict__ col_idx,
                                                    const float* __restrict__ cls_b,
                                                    float* __restrict__ logits,
                                                    int n, int K) {
    __shared__ int cnt[NBKT];
    __shared__ int sA[NBKT];
    __shared__ int cur[NBKT];
    int t = threadIdx.x;
    int b = blockIdx.x;
    if (b == 0 && t < NG) logits[t] = cls_b[0];
    int node0 = b * K;
    int nn = n - node0;
    if (nn > K) nn = K;
    if (nn < 0) nn = 0;
    int e0 = b * CAP;
    int e1 = e0 + bcurP[b * 16];
    cnt[t] = 0;
    __syncthreads();
    for (int e = e0 + t; e < e1; e += 256) {
        int ld = (int)(bpacked[e] >> 16) - node0;
        atomicAdd(&cnt[ld], 1);
    }
    __syncthreads();
    int c = cnt[t];
    sA[t] = c;
    __syncthreads();
    for (int off = 1; off < NBKT; off <<= 1) {
        int v = (t >= off) ? sA[t - off] : 0;
        __syncthreads();
        sA[t] += v;
        __syncthreads();
    }
    int rp = e0 + sA[t] - c;
    cur[t] = rp;
    if (t < nn) {
        row_ptr[node0 + t] = rp;
        degA[node0 + t] = c;
        dis[node0 + t] = rsqrtf((float)(c + 1));
    }
    __syncthreads();
    for (int e = e0 + t; e < e1; e += 256) {
        unsigned v = bpacked[e];
        int ld = (int)(v >> 16) - node0;
        int p = atomicAdd(&cur[ld], 1);
        col_idx[p] = (int)(v & 0xFFFFu);
    }
}

// =============== MFMA GEMM: outb = bf16( dis[row] * (in @ W) ) ===============

#define ASTR 136

__global__ __launch_bounds__(256) void k_gemm_mfma(const void* __restrict__ inp,
                                                   const unsigned short* __restrict__ wt,
                                                   const float* __restrict__ dis,
                                                   unsigned short* __restrict__ outb,
                                                   int n, int fmt) {
    __shared__ unsigned short A[64][ASTR];
    int t = threadIdx.x;
    int row0 = blockIdx.x * 64;

    if (fmt == 0) {          // f32 input
        const float* in = (const float*)inp;
        #pragma unroll
        for (int i = 0; i < 8; ++i) {
            int idx = t + i * 256;
            int r = idx >> 5;
            int c4 = (idx & 31) * 4;
            float4 v = make_float4(0.f, 0.f, 0.f, 0.f);
            if (row0 + r < n) v = *(const float4*)&in[(size_t)(row0 + r) * 128 + c4];
            uint2 p;
            p.x = pack_bf2(v.x, v.y);
            p.y = pack_bf2(v.z, v.w);
            *(uint2*)&A[r][c4] = p;
        }
    } else {                 // bf16 input
        const unsigned short* in = (const unsigned short*)inp;
        #pragma unroll
        for (int i = 0; i < 4; ++i) {
            int idx = t + i * 256;
            int r = idx >> 4;
            int c8 = (idx & 15) * 8;
            uint4 v = make_uint4(0, 0, 0, 0);
            if (row0 + r < n) v = *(const uint4*)&in[(size_t)(row0 + r) * 128 + c8];
            *(uint4*)&A[r][c8] = v;
        }
    }
    __syncthreads();

    int lane = t & 63;
    int wave = t >> 6;
    int m = lane & 15;
    int quad = lane >> 4;
    int r0 = wave * 16;

    short8 a[4];
    #pragma unroll
    for (int kt = 0; kt < 4; ++kt)
        a[kt] = *(const short8*)&A[r0 + m][kt * 32 + quad * 8];

    f32x4 acc[8];
    #pragma unroll
    for (int ct = 0; ct < 8; ++ct) acc[ct] = (f32x4){0.f, 0.f, 0.f, 0.f};

    // B-frag double-buffer: prefetch ct+1 while MFMAs consume ct
    short8 bcur[4], bnxt[4];
    {
        const unsigned short* wb = &wt[(size_t)m * 128 + quad * 8];
        #pragma unroll
        for (int kt = 0; kt < 4; ++kt) bcur[kt] = *(const short8*)(wb + kt * 32);
    }
    #pragma unroll
    for (int ct = 0; ct < 8; ++ct) {
        if (ct < 7) {
            const unsigned short* wb = &wt[(size_t)((ct + 1) * 16 + m) * 128 + quad * 8];
            #pragma unroll
            for (int kt = 0; kt < 4; ++kt) bnxt[kt] = *(const short8*)(wb + kt * 32);
        }
        #pragma unroll
        for (int kt = 0; kt < 4; ++kt)
            acc[ct] = __builtin_amdgcn_mfma_f32_16x16x32_bf16(a[kt], bcur[kt], acc[ct], 0, 0, 0);
        #pragma unroll
        for (int kt = 0; kt < 4; ++kt) bcur[kt] = bnxt[kt];
    }

    int gr = row0 + r0 + quad * 4;
    float ds[4];
    #pragma unroll
    for (int reg = 0; reg < 4; ++reg)
        ds[reg] = (gr + reg < n) ? dis[gr + reg] : 0.f;

    __syncthreads();
    #pragma unroll
    for (int ct = 0; ct < 8; ++ct) {
        int col = ct * 16 + m;
        #pragma unroll
        for (int reg = 0; reg < 4; ++reg)
            A[r0 + quad * 4 + reg][col] = bf16_1(acc[ct][reg] * ds[reg]);
    }
    __syncthreads();
    #pragma unroll
    for (int i = 0; i < 4; ++i) {
        int idx = t + i * 256;
        int r = idx >> 4;
        int c8 = (idx & 15) * 8;
        int grow = row0 + r;
        if (grow < n)
            *(uint4*)&outb[(size_t)grow * 128 + c8] = *(const uint4*)&A[r][c8];
    }
}

// =============== agg core: 16 lanes/node, 16 uint4 in flight, col_idx pipelined ===========

__device__ inline void gather4wide(const unsigned short* __restrict__ hwsb,
                                   const int* __restrict__ col_idx,
                                   int e0, int deg, int md,
                                   int sl, int part, bool active,
                                   float* acc8) {
    int cidx = (active && sl < deg) ? col_idx[e0 + sl] : 0;
    for (int it0 = 0; it0 < md; it0 += 16) {
        int nx = it0 + 16;
        int cidx_next = (active && (nx + sl) < deg && nx < md) ? col_idx[e0 + nx + sl] : 0;
        uint4 vv[16];
        #pragma unroll
        for (int j = 0; j < 16; ++j) {
            int s = __shfl(cidx, (part << 4) + j);
            vv[j] = (it0 + j < deg)
                        ? *(const uint4*)(hwsb + ((size_t)s << 7) + (sl << 3))
                        : make_uint4(0, 0, 0, 0);
        }
        #pragma unroll
        for (int j = 0; j < 16; ++j) {
            const unsigned* w = (const unsigned*)&vv[j];
            #pragma unroll
            for (int i2 = 0; i2 < 4; ++i2) {
                float2 f = unpack_bf2(w[i2]);
                acc8[2 * i2]     += f.x;
                acc8[2 * i2 + 1] += f.y;
            }
        }
        cidx = cidx_next;
    }
}

// ------- layer-1 aggregation + bias + BN + ReLU -> h1 (bf16); block=256, 16 nodes -------

__global__ __launch_bounds__(256) void k_agg_bn_relu(const unsigned short* __restrict__ hwsb,
                                                     const int* __restrict__ row_ptr,
                                                     const int* __restrict__ degA,
                                                     const int* __restrict__ col_idx,
                                                     const float* __restrict__ dis,
                                                     const float* __restrict__ bias,
                                                     const float* __restrict__ gamma,
                                                     const float* __restrict__ beta,
                                                     const float* __restrict__ mean,
                                                     const float* __restrict__ var,
                                                     unsigned short* __restrict__ outh, int n) {
    int t = threadIdx.x;
    int wave = t >> 6, lane = t & 63;
    int sl = lane & 15, part = lane >> 4;
    int d = blockIdx.x * 16 + wave * 4 + part;
    bool active = (d < n);
    int e0 = 0, deg = 0;
    if (active) {
        e0 = row_ptr[d];
        deg = degA[d];
    }
    int md = deg;
    md = max(md, __shfl_xor(md, 16));
    md = max(md, __shfl_xor(md, 32));

    float acc8[8] = {0, 0, 0, 0, 0, 0, 0, 0};
    gather4wide(hwsb, col_idx, e0, deg, md, sl, part, active, acc8);
    if (!active) return;

    {   // self
        uint4 v = *(const uint4*)(hwsb + ((size_t)d << 7) + (sl << 3));
        const unsigned* w = (const unsigned*)&v;
        #pragma unroll
        for (int i2 = 0; i2 < 4; ++i2) {
            float2 f = unpack_bf2(w[i2]);
            acc8[2 * i2]     += f.x;
            acc8[2 * i2 + 1] += f.y;
        }
    }
    float dd = dis[d];
    int f0 = sl << 3;
    unsigned outw[4];
    #pragma unroll
    for (int i2 = 0; i2 < 4; ++i2) {
        int f = f0 + 2 * i2;
        float2 bv = *(const float2*)&bias[f];
        float2 gm = *(const float2*)&gamma[f];
        float2 bt = *(const float2*)&beta[f];
        float2 mn = *(const float2*)&mean[f];
        float2 vr = *(const float2*)&var[f];
        float vx = acc8[2 * i2] * dd + bv.x;
        float vy = acc8[2 * i2 + 1] * dd + bv.y;
        float sx = gm.x * rsqrtf(vr.x + BN_EPS);
        float sy = gm.y * rsqrtf(vr.y + BN_EPS);
        float rx = fmaxf((vx - mn.x) * sx + bt.x, 0.f);
        float ry = fmaxf((vy - mn.y) * sy + bt.y, 0.f);
        outw[i2] = pack_bf2(rx, ry);
    }
    *(uint4*)(outh + ((size_t)d << 7) + (sl << 3)) = *(uint4*)outw;
}

// ------- layer-2 agg + BN + ReLU + attention + logits; block=256, 16 nodes -------

__global__ __launch_bounds__(256) void k_agg2_att_logit(const unsigned short* __restrict__ hwsb,
                                                        const int* __restrict__ row_ptr,
                                                        const int* __restrict__ degA,
                                                        const int* __restrict__ col_idx,
                                                        const float* __restrict__ dis,
                                                        const float* __restrict__ bias,
                                                        const float* __restrict__ gamma,
                                                        const float* __restrict__ beta,
                                                        const float* __restrict__ mean,
                                                        const float* __restrict__ var,
                                                        const int* __restrict__ batch,
                                                        const float* __restrict__ att_w,
                                                        const float* __restrict__ cls_w,
                                                        float* __restrict__ att_out,
                                                        float* __restrict__ logits, int n) {
    __shared__ int   sg[16];
    __shared__ float sv[16];
    int t = threadIdx.x;
    int wave = t >> 6, lane = t & 63;
    int sl = lane & 15, part = lane >> 4;
    int d = blockIdx.x * 16 + wave * 4 + part;
    bool active = (d < n);
    int e0 = 0, deg = 0;
    if (active) {
        e0 = row_ptr[d];
        deg = degA[d];
    }
    int md = deg;
    md = max(md, __shfl_xor(md, 16));
    md = max(md, __shfl_xor(md, 32));

    float acc8[8] = {0, 0, 0, 0, 0, 0, 0, 0};
    gather4wide(hwsb, col_idx, e0, deg, md, sl, part, active, acc8);

    int g = -1;
    float contrib = 0.f;
    float p = 0.f, q = 0.f;
    if (active) {
        uint4 v = *(const uint4*)(hwsb + ((size_t)d << 7) + (sl << 3));
        const unsigned* w = (const unsigned*)&v;
        #pragma unroll
        for (int i2 = 0; i2 < 4; ++i2) {
            float2 f = unpack_bf2(w[i2]);
            acc8[2 * i2]     += f.x;
            acc8[2 * i2 + 1] += f.y;
        }
        float dd = dis[d];
        int f0 = sl << 3;
        #pragma unroll
        for (int i2 = 0; i2 < 4; ++i2) {
            int f = f0 + 2 * i2;
            float2 bv = *(const float2*)&bias[f];
            float2 gm = *(const float2*)&gamma[f];
            float2 bt = *(const float2*)&beta[f];
            float2 mn = *(const float2*)&mean[f];
            float2 vr = *(const float2*)&var[f];
            float vx = acc8[2 * i2] * dd + bv.x;
            float vy = acc8[2 * i2 + 1] * dd + bv.y;
            float sx = gm.x * rsqrtf(vr.x + BN_EPS);
            float sy = gm.y * rsqrtf(vr.y + BN_EPS);
            float rx = fmaxf((vx - mn.x) * sx + bt.x, 0.f);
            float ry = fmaxf((vy - mn.y) * sy + bt.y, 0.f);
            float2 aw = *(const float2*)&att_w[f];
            float2 cw = *(const float2*)&cls_w[f];
            p += rx * aw.x + ry * aw.y;
            q += rx * cw.x + ry * cw.y;
        }
    }
    #pragma unroll
    for (int off = 1; off < 16; off <<= 1) {
        p += __shfl_xor(p, off);
        q += __shfl_xor(q, off);
    }
    if (active) {
        float a = 1.f / (1.f + expf(-p));
        if (sl == 0) att_out[d] = a;
        g = batch[d];
        contrib = a * q;
    }
    if (sl == 0) {
        sg[wave * 4 + part] = g;
        sv[wave * 4 + part] = contrib;
    }
    __syncthreads();
    if (t == 0) {
        int cur = -1;
        float acc = 0.f;
        #pragma unroll
        for (int i = 0; i < 16; ++i) {
            int gi = sg[i];
            if (gi < 0) continue;
            if (gi != cur) {
                if (cur >= 0) atomicAdd(&logits[cur], acc);
                cur = gi;
                acc = 0.f;
            }
            acc += sv[i];
        }
        if (cur >= 0) atomicAdd(&logits[cur], acc);
    }
}

// ---------------- launch ----------------

extern "C" void kernel_launch(void* const* d_in, const int* in_sizes, int n_in,
                              void* d_out, int out_size, void* d_ws, size_t ws_size,
                              hipStream_t stream) {
    const float* x   = (const float*)d_in[0];
    const int*   ei  = (const int*)d_in[1];
    const int*   bat = (const int*)d_in[2];
    const float* W1  = (const float*)d_in[3];
    const float* b1  = (const float*)d_in[4];
    const float* g1  = (const float*)d_in[5];
    const float* bt1 = (const float*)d_in[6];
    const float* mn1 = (const float*)d_in[7];
    const float* vr1 = (const float*)d_in[8];
    const float* W2  = (const float*)d_in[9];
    const float* b2  = (const float*)d_in[10];
    const float* g2  = (const float*)d_in[11];
    const float* bt2 = (const float*)d_in[12];
    const float* mn2 = (const float*)d_in[13];
    const float* vr2 = (const float*)d_in[14];
    const float* attw = (const float*)d_in[15];
    const float* clsw = (const float*)d_in[16];
    const float* clsb = (const float*)d_in[17];

    int E = in_sizes[1] / 2;
    int n = in_sizes[2];
    const int* src = ei;
    const int* dst = ei + E;
    int K = (n + NBKT - 1) / NBKT;

    char* ws = (char*)d_ws;
    auto alloc = [&](size_t bytes) {
        void* p = (void*)ws;
        ws += (bytes + 255) & ~(size_t)255;
        return p;
    };
    int*            bcurP   = (int*)alloc(NBKT * 16 * 4);
    unsigned*       bpacked = (unsigned*)alloc((size_t)NBKT * CAP * 4);
    int*            row_ptr = (int*)alloc((size_t)n * 4);
    int*            degA    = (int*)alloc((size_t)n * 4);
    int*            col_idx = (int*)alloc((size_t)NBKT * CAP * 4);
    float*          dis     = (float*)alloc((size_t)n * 4);
    unsigned short* hwsb    = (unsigned short*)alloc((size_t)n * 128 * 2);
    unsigned short* h1b     = (unsigned short*)alloc((size_t)n * 128 * 2);
    unsigned short* wt1     = (unsigned short*)alloc(128 * 128 * 2);
    unsigned short* wt2     = (unsigned short*)alloc(128 * 128 * 2);

    float* out = (float*)d_out;
    int etiles = (E + ETILE - 1) / ETILE;
    int gb = (n + 63) / 64;
    int ab = (n + 15) / 16;

    hipMemsetAsync(bcurP, 0, NBKT * 16 * 4, stream);
    k_distribute<<<etiles + 256, 256, 0, stream>>>(src, dst, bcurP, bpacked,
                                                   W1, W2, wt1, wt2, etiles, E, K);
    k_bucket_csr<<<NBKT, 256, 0, stream>>>(bpacked, bcurP, row_ptr, degA, dis,
                                           col_idx, clsb, out, n, K);

    k_gemm_mfma<<<gb, 256, 0, stream>>>(x, wt1, dis, hwsb, n, 0);
    k_agg_bn_relu<<<ab, 256, 0, stream>>>(hwsb, row_ptr, degA, col_idx, dis,
                                          b1, g1, bt1, mn1, vr1, h1b, n);
    k_gemm_mfma<<<gb, 256, 0, stream>>>(h1b, wt2, dis, hwsb, n, 1);
    k_agg2_att_logit<<<ab, 256, 0, stream>>>(hwsb, row_ptr, degA, col_idx, dis,
                                             b2, g2, bt2, mn2, vr2, bat, attw, clsw,
                                             out + NG, out, n);
}

// Round 15
// 293.699 us; speedup vs baseline: 1.0873x; 1.0521x over previous
//
#include <hip/hip_runtime.h>
#include <math.h>

#define NN 50000
#define HID 128
#define NG 64
#define BN_EPS 1e-5f

typedef __attribute__((ext_vector_type(8))) short short8;
typedef __attribute__((ext_vector_type(4))) float f32x4;

// ---- bf16 pack/unpack (RNE) ----
__device__ inline unsigned pack_bf2(float a, float b) {
    union { float f; unsigned u; } ua, ub;
    ua.f = a; ub.f = b;
    unsigned x = ua.u, y = ub.u;
    x += 0x7fffu + ((x >> 16) & 1u);
    y += 0x7fffu + ((y >> 16) & 1u);
    return (x >> 16) | (y & 0xffff0000u);
}
__device__ inline unsigned short bf16_1(float x) {
    union { float f; unsigned u; } v;
    v.f = x;
    unsigned r = v.u + 0x7fffu + ((v.u >> 16) & 1u);
    return (unsigned short)(r >> 16);
}
__device__ inline float2 unpack_bf2(unsigned v) {
    union { unsigned u; float f; } a, b;
    a.u = v << 16;
    b.u = v & 0xffff0000u;
    return make_float2(a.f, b.f);
}

// =============== bucketed CSR build — fixed-capacity buckets ===============
// bcurP holds RELATIVE cursors (zeroed by hipMemsetAsync); segment b = [b*CAP, ...).
#define NBKT 256
#define ETILE 8192
#define CAP   8192

// blocks < etiles: scatter packed edges into bucket segments.
// blocks >= etiles: W transpose+bf16 (consumed only after next kernel boundary).
__global__ __launch_bounds__(256) void k_distribute(const int* __restrict__ src,
                                                    const int* __restrict__ dst,
                                                    int* __restrict__ bcurP,
                                                    unsigned* __restrict__ bpacked,
                                                    const float* __restrict__ W1,
                                                    const float* __restrict__ W2,
                                                    unsigned short* __restrict__ wt1,
                                                    unsigned short* __restrict__ wt2,
                                                    int etiles, int E, int K) {
    if ((int)blockIdx.x >= etiles) {
        int b2 = blockIdx.x - etiles;          // 0..255
        int k = b2 & 127;
        const float* W = (b2 < 128) ? W1 : W2;
        unsigned short* wt = (b2 < 128) ? wt1 : wt2;
        int c = threadIdx.x;
        if (c < 128) wt[c * 128 + k] = bf16_1(W[k * 128 + c]);
        return;
    }
    __shared__ int h[NBKT];
    int t = threadIdx.x;
    h[t] = 0;
    __syncthreads();
    int base = blockIdx.x * ETILE;
    for (int i = 0; i < ETILE / 256; ++i) {
        int e = base + i * 256 + t;
        if (e < E) atomicAdd(&h[dst[e] / K], 1);
    }
    __syncthreads();
    int c = h[t];
    int my = (c > 0) ? atomicAdd(&bcurP[t * 16], c) : 0;   // relative base
    __syncthreads();
    h[t] = my;
    __syncthreads();
    for (int i = 0; i < ETILE / 256; ++i) {
        int e = base + i * 256 + t;
        if (e < E) {
            int d = dst[e];
            int bkt = d / K;
            int p = atomicAdd(&h[bkt], 1);
            bpacked[(size_t)bkt * CAP + p] = ((unsigned)d << 16) | (unsigned)src[e];
        }
    }
}

// one block per bucket: LDS counting sort -> row_ptr/deg/dis + col_idx.
// block 0 also seeds logits with cls_b.
__global__ __launch_bounds__(256) void k_bucket_csr(const unsigned* __restrict__ bpacked,
                                                    const int* __restrict__ bcurP,
                                                    int* __restrict__ row_ptr,
                                                    int* __restrict__ degA,
                                                    float* __restrict__ dis,
                                                    int* __restrict__ col_idx,
                                                    const float* __restrict__ cls_b,
                                                    float* __restrict__ logits,
                                                    int n, int K) {
    __shared__ int cnt[NBKT];
    __shared__ int sA[NBKT];
    __shared__ int cur[NBKT];
    int t = threadIdx.x;
    int b = blockIdx.x;
    if (b == 0 && t < NG) logits[t] = cls_b[0];
    int node0 = b * K;
    int nn = n - node0;
    if (nn > K) nn = K;
    if (nn < 0) nn = 0;
    int e0 = b * CAP;
    int e1 = e0 + bcurP[b * 16];
    cnt[t] = 0;
    __syncthreads();
    for (int e = e0 + t; e < e1; e += 256) {
        int ld = (int)(bpacked[e] >> 16) - node0;
        atomicAdd(&cnt[ld], 1);
    }
    __syncthreads();
    int c = cnt[t];
    sA[t] = c;
    __syncthreads();
    for (int off = 1; off < NBKT; off <<= 1) {
        int v = (t >= off) ? sA[t - off] : 0;
        __syncthreads();
        sA[t] += v;
        __syncthreads();
    }
    int rp = e0 + sA[t] - c;
    cur[t] = rp;
    if (t < nn) {
        row_ptr[node0 + t] = rp;
        degA[node0 + t] = c;
        dis[node0 + t] = rsqrtf((float)(c + 1));
    }
    __syncthreads();
    for (int e = e0 + t; e < e1; e += 256) {
        unsigned v = bpacked[e];
        int ld = (int)(v >> 16) - node0;
        int p = atomicAdd(&cur[ld], 1);
        col_idx[p] = (int)(v & 0xFFFFu);
    }
}

// =============== MFMA GEMM (layer 1): outb = bf16( dis[row] * (in @ W) ) ===============

#define ASTR 136

__global__ __launch_bounds__(256) void k_gemm_mfma(const float* __restrict__ in,
                                                   const unsigned short* __restrict__ wt,
                                                   const float* __restrict__ dis,
                                                   unsigned short* __restrict__ outb, int n) {
    __shared__ unsigned short A[64][ASTR];
    int t = threadIdx.x;
    int row0 = blockIdx.x * 64;

    #pragma unroll
    for (int i = 0; i < 8; ++i) {
        int idx = t + i * 256;
        int r = idx >> 5;
        int c4 = (idx & 31) * 4;
        float4 v = make_float4(0.f, 0.f, 0.f, 0.f);
        if (row0 + r < n) v = *(const float4*)&in[(size_t)(row0 + r) * 128 + c4];
        uint2 p;
        p.x = pack_bf2(v.x, v.y);
        p.y = pack_bf2(v.z, v.w);
        *(uint2*)&A[r][c4] = p;
    }
    __syncthreads();

    int lane = t & 63;
    int wave = t >> 6;
    int m = lane & 15;
    int quad = lane >> 4;
    int r0 = wave * 16;

    short8 a[4];
    #pragma unroll
    for (int kt = 0; kt < 4; ++kt)
        a[kt] = *(const short8*)&A[r0 + m][kt * 32 + quad * 8];

    f32x4 acc[8];
    #pragma unroll
    for (int ct = 0; ct < 8; ++ct) acc[ct] = (f32x4){0.f, 0.f, 0.f, 0.f};

    // B-frag double-buffer: prefetch ct+1 while MFMAs consume ct
    short8 bcur[4], bnxt[4];
    {
        const unsigned short* wb = &wt[(size_t)m * 128 + quad * 8];
        #pragma unroll
        for (int kt = 0; kt < 4; ++kt) bcur[kt] = *(const short8*)(wb + kt * 32);
    }
    #pragma unroll
    for (int ct = 0; ct < 8; ++ct) {
        if (ct < 7) {
            const unsigned short* wb = &wt[(size_t)((ct + 1) * 16 + m) * 128 + quad * 8];
            #pragma unroll
            for (int kt = 0; kt < 4; ++kt) bnxt[kt] = *(const short8*)(wb + kt * 32);
        }
        #pragma unroll
        for (int kt = 0; kt < 4; ++kt)
            acc[ct] = __builtin_amdgcn_mfma_f32_16x16x32_bf16(a[kt], bcur[kt], acc[ct], 0, 0, 0);
        #pragma unroll
        for (int kt = 0; kt < 4; ++kt) bcur[kt] = bnxt[kt];
    }

    int gr = row0 + r0 + quad * 4;
    float ds[4];
    #pragma unroll
    for (int reg = 0; reg < 4; ++reg)
        ds[reg] = (gr + reg < n) ? dis[gr + reg] : 0.f;

    __syncthreads();
    #pragma unroll
    for (int ct = 0; ct < 8; ++ct) {
        int col = ct * 16 + m;
        #pragma unroll
        for (int reg = 0; reg < 4; ++reg)
            A[r0 + quad * 4 + reg][col] = bf16_1(acc[ct][reg] * ds[reg]);
    }
    __syncthreads();
    #pragma unroll
    for (int i = 0; i < 4; ++i) {
        int idx = t + i * 256;
        int r = idx >> 4;
        int c8 = (idx & 15) * 8;
        int grow = row0 + r;
        if (grow < n)
            *(uint4*)&outb[(size_t)grow * 128 + c8] = *(const uint4*)&A[r][c8];
    }
}

// =============== agg core: 16 lanes/node, 16 uint4 in flight, col_idx pipelined ===========

__device__ inline void gather4wide(const unsigned short* __restrict__ hwsb,
                                   const int* __restrict__ col_idx,
                                   int e0, int deg, int md,
                                   int sl, int part, bool active,
                                   float* acc8) {
    int cidx = (active && sl < deg) ? col_idx[e0 + sl] : 0;
    for (int it0 = 0; it0 < md; it0 += 16) {
        int nx = it0 + 16;
        int cidx_next = (active && (nx + sl) < deg && nx < md) ? col_idx[e0 + nx + sl] : 0;
        uint4 vv[16];
        #pragma unroll
        for (int j = 0; j < 16; ++j) {
            int s = __shfl(cidx, (part << 4) + j);
            vv[j] = (it0 + j < deg)
                        ? *(const uint4*)(hwsb + ((size_t)s << 7) + (sl << 3))
                        : make_uint4(0, 0, 0, 0);
        }
        #pragma unroll
        for (int j = 0; j < 16; ++j) {
            const unsigned* w = (const unsigned*)&vv[j];
            #pragma unroll
            for (int i2 = 0; i2 < 4; ++i2) {
                float2 f = unpack_bf2(w[i2]);
                acc8[2 * i2]     += f.x;
                acc8[2 * i2 + 1] += f.y;
            }
        }
        cidx = cidx_next;
    }
}

// ------- FUSED: layer-1 agg + BN + ReLU -> h1 (LDS) -> GEMM2 -> hws2 (global bf16) -------
// Block owns 16 contiguous nodes = a full 16x128 h1 tile; gemm2 done in-block via MFMA.

__global__ __launch_bounds__(256) void k_agg1_gemm2(const unsigned short* __restrict__ hwsb1,
                                                    const int* __restrict__ row_ptr,
                                                    const int* __restrict__ degA,
                                                    const int* __restrict__ col_idx,
                                                    const float* __restrict__ dis,
                                                    const float* __restrict__ bias,
                                                    const float* __restrict__ gamma,
                                                    const float* __restrict__ beta,
                                                    const float* __restrict__ mean,
                                                    const float* __restrict__ var,
                                                    const unsigned short* __restrict__ wt2,
                                                    unsigned short* __restrict__ hwsb2, int n) {
    __shared__ unsigned short H1[16][ASTR];
    __shared__ unsigned short C2[16][ASTR];
    int t = threadIdx.x;
    int wave = t >> 6, lane = t & 63;
    int sl = lane & 15, part = lane >> 4;
    int d = blockIdx.x * 16 + wave * 4 + part;
    bool active = (d < n);
    int e0 = 0, deg = 0;
    if (active) {
        e0 = row_ptr[d];
        deg = degA[d];
    }
    int md = deg;
    md = max(md, __shfl_xor(md, 16));
    md = max(md, __shfl_xor(md, 32));

    float acc8[8] = {0, 0, 0, 0, 0, 0, 0, 0};
    gather4wide(hwsb1, col_idx, e0, deg, md, sl, part, active, acc8);

    unsigned outw[4] = {0, 0, 0, 0};
    if (active) {
        uint4 v = *(const uint4*)(hwsb1 + ((size_t)d << 7) + (sl << 3));
        const unsigned* w = (const unsigned*)&v;
        #pragma unroll
        for (int i2 = 0; i2 < 4; ++i2) {
            float2 f = unpack_bf2(w[i2]);
            acc8[2 * i2]     += f.x;
            acc8[2 * i2 + 1] += f.y;
        }
        float dd = dis[d];
        int f0 = sl << 3;
        #pragma unroll
        for (int i2 = 0; i2 < 4; ++i2) {
            int f = f0 + 2 * i2;
            float2 bv = *(const float2*)&bias[f];
            float2 gm = *(const float2*)&gamma[f];
            float2 bt = *(const float2*)&beta[f];
            float2 mn = *(const float2*)&mean[f];
            float2 vr = *(const float2*)&var[f];
            float vx = acc8[2 * i2] * dd + bv.x;
            float vy = acc8[2 * i2 + 1] * dd + bv.y;
            float sx = gm.x * rsqrtf(vr.x + BN_EPS);
            float sy = gm.y * rsqrtf(vr.y + BN_EPS);
            float rx = fmaxf((vx - mn.x) * sx + bt.x, 0.f);
            float ry = fmaxf((vy - mn.y) * sy + bt.y, 0.f);
            outw[i2] = pack_bf2(rx, ry);
        }
    }
    int local = wave * 4 + part;
    *(uint4*)&H1[local][sl << 3] = *(uint4*)outw;
    __syncthreads();

    // ---- GEMM2 phase: hws2[16 rows] = dis * (H1 @ W2), wave w covers cols [w*32, w*32+32) ----
    int m = sl;          // lane&15
    int quad = part;     // lane>>4
    short8 a2[4];
    #pragma unroll
    for (int kt = 0; kt < 4; ++kt)
        a2[kt] = *(const short8*)&H1[m][kt * 32 + quad * 8];

    f32x4 acc2[2];
    acc2[0] = (f32x4){0.f, 0.f, 0.f, 0.f};
    acc2[1] = (f32x4){0.f, 0.f, 0.f, 0.f};
    #pragma unroll
    for (int i = 0; i < 2; ++i) {
        int ct = wave * 2 + i;
        const unsigned short* wb = &wt2[(size_t)(ct * 16 + m) * 128 + quad * 8];
        #pragma unroll
        for (int kt = 0; kt < 4; ++kt) {
            short8 b = *(const short8*)(wb + kt * 32);
            acc2[i] = __builtin_amdgcn_mfma_f32_16x16x32_bf16(a2[kt], b, acc2[i], 0, 0, 0);
        }
    }
    int gr = blockIdx.x * 16 + quad * 4;
    float ds2[4];
    #pragma unroll
    for (int reg = 0; reg < 4; ++reg)
        ds2[reg] = (gr + reg < n) ? dis[gr + reg] : 0.f;
    #pragma unroll
    for (int i = 0; i < 2; ++i) {
        int col = (wave * 2 + i) * 16 + m;
        #pragma unroll
        for (int reg = 0; reg < 4; ++reg)
            C2[quad * 4 + reg][col] = bf16_1(acc2[i][reg] * ds2[reg]);
    }
    __syncthreads();
    {
        int r = t >> 4;
        int c8 = (t & 15) * 8;
        int grow = blockIdx.x * 16 + r;
        if (grow < n)
            *(uint4*)&hwsb2[(size_t)grow * 128 + c8] = *(const uint4*)&C2[r][c8];
    }
}

// ------- layer-2 agg + BN + ReLU + attention + logits; block=256, 16 nodes -------

__global__ __launch_bounds__(256) void k_agg2_att_logit(const unsigned short* __restrict__ hwsb,
                                                        const int* __restrict__ row_ptr,
                                                        const int* __restrict__ degA,
                                                        const int* __restrict__ col_idx,
                                                        const float* __restrict__ dis,
                                                        const float* __restrict__ bias,
                                                        const float* __restrict__ gamma,
                                                        const float* __restrict__ beta,
                                                        const float* __restrict__ mean,
                                                        const float* __restrict__ var,
                                                        const int* __restrict__ batch,
                                                        const float* __restrict__ att_w,
                                                        const float* __restrict__ cls_w,
                                                        float* __restrict__ att_out,
                                                        float* __restrict__ logits, int n) {
    __shared__ int   sg[16];
    __shared__ float sv[16];
    int t = threadIdx.x;
    int wave = t >> 6, lane = t & 63;
    int sl = lane & 15, part = lane >> 4;
    int d = blockIdx.x * 16 + wave * 4 + part;
    bool active = (d < n);
    int e0 = 0, deg = 0;
    if (active) {
        e0 = row_ptr[d];
        deg = degA[d];
    }
    int md = deg;
    md = max(md, __shfl_xor(md, 16));
    md = max(md, __shfl_xor(md, 32));

    float acc8[8] = {0, 0, 0, 0, 0, 0, 0, 0};
    gather4wide(hwsb, col_idx, e0, deg, md, sl, part, active, acc8);

    int g = -1;
    float contrib = 0.f;
    float p = 0.f, q = 0.f;
    if (active) {
        uint4 v = *(const uint4*)(hwsb + ((size_t)d << 7) + (sl << 3));
        const unsigned* w = (const unsigned*)&v;
        #pragma unroll
        for (int i2 = 0; i2 < 4; ++i2) {
            float2 f = unpack_bf2(w[i2]);
            acc8[2 * i2]     += f.x;
            acc8[2 * i2 + 1] += f.y;
        }
        float dd = dis[d];
        int f0 = sl << 3;
        #pragma unroll
        for (int i2 = 0; i2 < 4; ++i2) {
            int f = f0 + 2 * i2;
            float2 bv = *(const float2*)&bias[f];
            float2 gm = *(const float2*)&gamma[f];
            float2 bt = *(const float2*)&beta[f];
            float2 mn = *(const float2*)&mean[f];
            float2 vr = *(const float2*)&var[f];
            float vx = acc8[2 * i2] * dd + bv.x;
            float vy = acc8[2 * i2 + 1] * dd + bv.y;
            float sx = gm.x * rsqrtf(vr.x + BN_EPS);
            float sy = gm.y * rsqrtf(vr.y + BN_EPS);
            float rx = fmaxf((vx - mn.x) * sx + bt.x, 0.f);
            float ry = fmaxf((vy - mn.y) * sy + bt.y, 0.f);
            float2 aw = *(const float2*)&att_w[f];
            float2 cw = *(const float2*)&cls_w[f];
            p += rx * aw.x + ry * aw.y;
            q += rx * cw.x + ry * cw.y;
        }
    }
    #pragma unroll
    for (int off = 1; off < 16; off <<= 1) {
        p += __shfl_xor(p, off);
        q += __shfl_xor(q, off);
    }
    if (active) {
        float a = 1.f / (1.f + expf(-p));
        if (sl == 0) att_out[d] = a;
        g = batch[d];
        contrib = a * q;
    }
    if (sl == 0) {
        sg[wave * 4 + part] = g;
        sv[wave * 4 + part] = contrib;
    }
    __syncthreads();
    if (t == 0) {
        int cur = -1;
        float acc = 0.f;
        #pragma unroll
        for (int i = 0; i < 16; ++i) {
            int gi = sg[i];
            if (gi < 0) continue;
            if (gi != cur) {
                if (cur >= 0) atomicAdd(&logits[cur], acc);
                cur = gi;
                acc = 0.f;
            }
            acc += sv[i];
        }
        if (cur >= 0) atomicAdd(&logits[cur], acc);
    }
}

// ---------------- launch ----------------

extern "C" void kernel_launch(void* const* d_in, const int* in_sizes, int n_in,
                              void* d_out, int out_size, void* d_ws, size_t ws_size,
                              hipStream_t stream) {
    const float* x   = (const float*)d_in[0];
    const int*   ei  = (const int*)d_in[1];
    const int*   bat = (const int*)d_in[2];
    const float* W1  = (const float*)d_in[3];
    const float* b1  = (const float*)d_in[4];
    const float* g1  = (const float*)d_in[5];
    const float* bt1 = (const float*)d_in[6];
    const float* mn1 = (const float*)d_in[7];
    const float* vr1 = (const float*)d_in[8];
    const float* W2  = (const float*)d_in[9];
    const float* b2  = (const float*)d_in[10];
    const float* g2  = (const float*)d_in[11];
    const float* bt2 = (const float*)d_in[12];
    const float* mn2 = (const float*)d_in[13];
    const float* vr2 = (const float*)d_in[14];
    const float* attw = (const float*)d_in[15];
    const float* clsw = (const float*)d_in[16];
    const float* clsb = (const float*)d_in[17];

    int E = in_sizes[1] / 2;
    int n = in_sizes[2];
    const int* src = ei;
    const int* dst = ei + E;
    int K = (n + NBKT - 1) / NBKT;

    char* ws = (char*)d_ws;
    auto alloc = [&](size_t bytes) {
        void* p = (void*)ws;
        ws += (bytes + 255) & ~(size_t)255;
        return p;
    };
    int*            bcurP   = (int*)alloc(NBKT * 16 * 4);
    unsigned*       bpacked = (unsigned*)alloc((size_t)NBKT * CAP * 4);
    int*            row_ptr = (int*)alloc((size_t)n * 4);
    int*            degA    = (int*)alloc((size_t)n * 4);
    int*            col_idx = (int*)alloc((size_t)NBKT * CAP * 4);
    float*          dis     = (float*)alloc((size_t)n * 4);
    unsigned short* hwsb1   = (unsigned short*)alloc((size_t)n * 128 * 2);
    unsigned short* hwsb2   = (unsigned short*)alloc((size_t)n * 128 * 2);
    unsigned short* wt1     = (unsigned short*)alloc(128 * 128 * 2);
    unsigned short* wt2     = (unsigned short*)alloc(128 * 128 * 2);

    float* out = (float*)d_out;
    int etiles = (E + ETILE - 1) / ETILE;
    int gb = (n + 63) / 64;
    int ab = (n + 15) / 16;

    hipMemsetAsync(bcurP, 0, NBKT * 16 * 4, stream);
    k_distribute<<<etiles + 256, 256, 0, stream>>>(src, dst, bcurP, bpacked,
                                                   W1, W2, wt1, wt2, etiles, E, K);
    k_bucket_csr<<<NBKT, 256, 0, stream>>>(bpacked, bcurP, row_ptr, degA, dis,
                                           col_idx, clsb, out, n, K);

    k_gemm_mfma<<<gb, 256, 0, stream>>>(x, wt1, dis, hwsb1, n);
    k_agg1_gemm2<<<ab, 256, 0, stream>>>(hwsb1, row_ptr, degA, col_idx, dis,
                                         b1, g1, bt1, mn1, vr1, wt2, hwsb2, n);
    k_agg2_att_logit<<<ab, 256, 0, stream>>>(hwsb2, row_ptr, degA, col_idx, dis,
                                             b2, g2, bt2, mn2, vr2, bat, attw, clsw,
                                             out + NG, out, n);
}

// Round 16
// 287.613 us; speedup vs baseline: 1.1103x; 1.0212x over previous
//
#include <hip/hip_runtime.h>
#include <math.h>

#define NN 50000
#define HID 128
#define NG 64
#define BN_EPS 1e-5f

typedef __attribute__((ext_vector_type(8))) short short8;
typedef __attribute__((ext_vector_type(4))) float f32x4;

// ---- bf16 pack/unpack (RNE) ----
__device__ inline unsigned pack_bf2(float a, float b) {
    union { float f; unsigned u; } ua, ub;
    ua.f = a; ub.f = b;
    unsigned x = ua.u, y = ub.u;
    x += 0x7fffu + ((x >> 16) & 1u);
    y += 0x7fffu + ((y >> 16) & 1u);
    return (x >> 16) | (y & 0xffff0000u);
}
__device__ inline unsigned short bf16_1(float x) {
    union { float f; unsigned u; } v;
    v.f = x;
    unsigned r = v.u + 0x7fffu + ((v.u >> 16) & 1u);
    return (unsigned short)(r >> 16);
}
__device__ inline float2 unpack_bf2(unsigned v) {
    union { unsigned u; float f; } a, b;
    a.u = v << 16;
    b.u = v & 0xffff0000u;
    return make_float2(a.f, b.f);
}

// =============== CSR build — fixed-capacity buckets ===============
#define NBKT 256
#define ETILE 8192
#define CAP   8192
#define ASTR 136

// prep: blocks 0..255 W transpose+bf16; block 256 zero cursors + seed logits
__global__ __launch_bounds__(128) void k_prep0(const float* __restrict__ W1,
                                               const float* __restrict__ W2,
                                               unsigned short* __restrict__ wt1,
                                               unsigned short* __restrict__ wt2,
                                               int* __restrict__ bcurP,
                                               const float* __restrict__ cls_b,
                                               float* __restrict__ logits) {
    int b = blockIdx.x;
    int t = threadIdx.x;
    if (b < 256) {
        int k = b & 127;
        const float* W = (b < 128) ? W1 : W2;
        unsigned short* wt = (b < 128) ? wt1 : wt2;
        wt[t * 128 + k] = bf16_1(W[k * 128 + t]);
    } else {
        #pragma unroll
        for (int i = 0; i < 32; ++i) bcurP[t * 32 + i] = 0;
        if (t < NG) logits[t] = cls_b[0];
    }
}

// pure scatter of packed edges into bucket segments (relative cursors)
__global__ __launch_bounds__(256) void k_distribute(const int* __restrict__ src,
                                                    const int* __restrict__ dst,
                                                    int* __restrict__ bcurP,
                                                    unsigned* __restrict__ bpacked,
                                                    int E, int K) {
    __shared__ int h[NBKT];
    int t = threadIdx.x;
    h[t] = 0;
    __syncthreads();
    int base = blockIdx.x * ETILE;
    for (int i = 0; i < ETILE / 256; ++i) {
        int e = base + i * 256 + t;
        if (e < E) atomicAdd(&h[dst[e] / K], 1);
    }
    __syncthreads();
    int c = h[t];
    int my = (c > 0) ? atomicAdd(&bcurP[t * 16], c) : 0;
    __syncthreads();
    h[t] = my;
    __syncthreads();
    for (int i = 0; i < ETILE / 256; ++i) {
        int e = base + i * 256 + t;
        if (e < E) {
            int d = dst[e];
            int bkt = d / K;
            int p = atomicAdd(&h[bkt], 1);
            bpacked[(size_t)bkt * CAP + p] = ((unsigned)d << 16) | (unsigned)src[e];
        }
    }
}

// blocks < NBKT: bucket CSR counting sort. blocks >= NBKT: gemm1 z = bf16(x@W1) UNSCALED
// (no dis dependency -> co-schedules with the CSR blocks).
__global__ __launch_bounds__(256) void k_csr_gemm1(const unsigned* __restrict__ bpacked,
                                                   const int* __restrict__ bcurP,
                                                   int* __restrict__ row_ptr,
                                                   int* __restrict__ degA,
                                                   float* __restrict__ dis,
                                                   int* __restrict__ col_idx,
                                                   const float* __restrict__ x,
                                                   const unsigned short* __restrict__ wt1,
                                                   unsigned short* __restrict__ zb,
                                                   int n, int K) {
    __shared__ unsigned short A[64][ASTR];   // gemm path (17.4 KB)
    __shared__ int cnt[NBKT];                // csr path (3 KB)
    __shared__ int sA[NBKT];
    __shared__ int cur[NBKT];
    int t = threadIdx.x;
    int b = blockIdx.x;

    if (b >= NBKT) {
        // ---------------- gemm1 path ----------------
        int row0 = (b - NBKT) * 64;
        #pragma unroll
        for (int i = 0; i < 8; ++i) {
            int idx = t + i * 256;
            int r = idx >> 5;
            int c4 = (idx & 31) * 4;
            float4 v = make_float4(0.f, 0.f, 0.f, 0.f);
            if (row0 + r < n) v = *(const float4*)&x[(size_t)(row0 + r) * 128 + c4];
            uint2 p;
            p.x = pack_bf2(v.x, v.y);
            p.y = pack_bf2(v.z, v.w);
            *(uint2*)&A[r][c4] = p;
        }
        __syncthreads();
        int lane = t & 63;
        int wave = t >> 6;
        int m = lane & 15;
        int quad = lane >> 4;
        int r0 = wave * 16;
        short8 a[4];
        #pragma unroll
        for (int kt = 0; kt < 4; ++kt)
            a[kt] = *(const short8*)&A[r0 + m][kt * 32 + quad * 8];
        f32x4 acc[8];
        #pragma unroll
        for (int ct = 0; ct < 8; ++ct) acc[ct] = (f32x4){0.f, 0.f, 0.f, 0.f};
        short8 bcur[4], bnxt[4];
        {
            const unsigned short* wb = &wt1[(size_t)m * 128 + quad * 8];
            #pragma unroll
            for (int kt = 0; kt < 4; ++kt) bcur[kt] = *(const short8*)(wb + kt * 32);
        }
        #pragma unroll
        for (int ct = 0; ct < 8; ++ct) {
            if (ct < 7) {
                const unsigned short* wb = &wt1[(size_t)((ct + 1) * 16 + m) * 128 + quad * 8];
                #pragma unroll
                for (int kt = 0; kt < 4; ++kt) bnxt[kt] = *(const short8*)(wb + kt * 32);
            }
            #pragma unroll
            for (int kt = 0; kt < 4; ++kt)
                acc[ct] = __builtin_amdgcn_mfma_f32_16x16x32_bf16(a[kt], bcur[kt], acc[ct], 0, 0, 0);
            #pragma unroll
            for (int kt = 0; kt < 4; ++kt) bcur[kt] = bnxt[kt];
        }
        __syncthreads();
        #pragma unroll
        for (int ct = 0; ct < 8; ++ct) {
            int col = ct * 16 + m;
            #pragma unroll
            for (int reg = 0; reg < 4; ++reg)
                A[r0 + quad * 4 + reg][col] = bf16_1(acc[ct][reg]);
        }
        __syncthreads();
        #pragma unroll
        for (int i = 0; i < 4; ++i) {
            int idx = t + i * 256;
            int r = idx >> 4;
            int c8 = (idx & 15) * 8;
            int grow = row0 + r;
            if (grow < n)
                *(uint4*)&zb[(size_t)grow * 128 + c8] = *(const uint4*)&A[r][c8];
        }
        return;
    }

    // ---------------- bucket CSR path ----------------
    int node0 = b * K;
    int nn = n - node0;
    if (nn > K) nn = K;
    if (nn < 0) nn = 0;
    int e0 = b * CAP;
    int e1 = e0 + bcurP[b * 16];
    cnt[t] = 0;
    __syncthreads();
    for (int e = e0 + t; e < e1; e += 256) {
        int ld = (int)(bpacked[e] >> 16) - node0;
        atomicAdd(&cnt[ld], 1);
    }
    __syncthreads();
    int c = cnt[t];
    sA[t] = c;
    __syncthreads();
    for (int off = 1; off < NBKT; off <<= 1) {
        int v = (t >= off) ? sA[t - off] : 0;
        __syncthreads();
        sA[t] += v;
        __syncthreads();
    }
    int rp = e0 + sA[t] - c;
    cur[t] = rp;
    if (t < nn) {
        row_ptr[node0 + t] = rp;
        degA[node0 + t] = c;
        dis[node0 + t] = rsqrtf((float)(c + 1));
    }
    __syncthreads();
    for (int e = e0 + t; e < e1; e += 256) {
        unsigned v = bpacked[e];
        int ld = (int)(v >> 16) - node0;
        int p = atomicAdd(&cur[ld], 1);
        col_idx[p] = (int)(v & 0xFFFFu);
    }
}

// =============== agg cores: 16 lanes/node, 16 uint4 in flight ===============

// plain (operand pre-scaled by dis)
__device__ inline void gather4wide(const unsigned short* __restrict__ hwsb,
                                   const int* __restrict__ col_idx,
                                   int e0, int deg, int md,
                                   int sl, int part, bool active,
                                   float* acc8) {
    int cidx = (active && sl < deg) ? col_idx[e0 + sl] : 0;
    for (int it0 = 0; it0 < md; it0 += 16) {
        int nx = it0 + 16;
        int cidx_next = (active && (nx + sl) < deg && nx < md) ? col_idx[e0 + nx + sl] : 0;
        uint4 vv[16];
        #pragma unroll
        for (int j = 0; j < 16; ++j) {
            int s = __shfl(cidx, (part << 4) + j);
            vv[j] = (it0 + j < deg)
                        ? *(const uint4*)(hwsb + ((size_t)s << 7) + (sl << 3))
                        : make_uint4(0, 0, 0, 0);
        }
        #pragma unroll
        for (int j = 0; j < 16; ++j) {
            const unsigned* w = (const unsigned*)&vv[j];
            #pragma unroll
            for (int i2 = 0; i2 < 4; ++i2) {
                float2 f = unpack_bf2(w[i2]);
                acc8[2 * i2]     += f.x;
                acc8[2 * i2 + 1] += f.y;
            }
        }
        cidx = cidx_next;
    }
}

// scaled: operand is UNSCALED z; multiply each neighbor row by dis[s] (L2-resident 200KB)
__device__ inline void gather4wide_scaled(const unsigned short* __restrict__ zb,
                                          const int* __restrict__ col_idx,
                                          const float* __restrict__ dis,
                                          int e0, int deg, int md,
                                          int sl, int part, bool active,
                                          float* acc8) {
    int cidx = (active && sl < deg) ? col_idx[e0 + sl] : 0;
    float cdis = (active && sl < deg) ? dis[cidx] : 0.f;
    for (int it0 = 0; it0 < md; it0 += 16) {
        int nx = it0 + 16;
        bool okn = (active && (nx + sl) < deg && nx < md);
        int cidx_next = okn ? col_idx[e0 + nx + sl] : 0;
        float cdis_next = okn ? dis[cidx_next] : 0.f;
        uint4 vv[16];
        float dsj[16];
        #pragma unroll
        for (int j = 0; j < 16; ++j) {
            int s = __shfl(cidx, (part << 4) + j);
            dsj[j] = __shfl(cdis, (part << 4) + j);
            vv[j] = (it0 + j < deg)
                        ? *(const uint4*)(zb + ((size_t)s << 7) + (sl << 3))
                        : make_uint4(0, 0, 0, 0);
        }
        #pragma unroll
        for (int j = 0; j < 16; ++j) {
            const unsigned* w = (const unsigned*)&vv[j];
            #pragma unroll
            for (int i2 = 0; i2 < 4; ++i2) {
                float2 f = unpack_bf2(w[i2]);
                acc8[2 * i2]     = fmaf(f.x, dsj[j], acc8[2 * i2]);
                acc8[2 * i2 + 1] = fmaf(f.y, dsj[j], acc8[2 * i2 + 1]);
            }
        }
        cidx = cidx_next;
        cdis = cdis_next;
    }
}

// ------- FUSED: layer-1 agg (scaled gather) + BN + ReLU -> h1 (LDS) -> GEMM2 -> hws2 -------

__global__ __launch_bounds__(256) void k_agg1_gemm2(const unsigned short* __restrict__ zb,
                                                    const int* __restrict__ row_ptr,
                                                    const int* __restrict__ degA,
                                                    const int* __restrict__ col_idx,
                                                    const float* __restrict__ dis,
                                                    const float* __restrict__ bias,
                                                    const float* __restrict__ gamma,
                                                    const float* __restrict__ beta,
                                                    const float* __restrict__ mean,
                                                    const float* __restrict__ var,
                                                    const unsigned short* __restrict__ wt2,
                                                    unsigned short* __restrict__ hwsb2, int n) {
    __shared__ unsigned short H1[16][ASTR];
    __shared__ unsigned short C2[16][ASTR];
    int t = threadIdx.x;
    int wave = t >> 6, lane = t & 63;
    int sl = lane & 15, part = lane >> 4;
    int d = blockIdx.x * 16 + wave * 4 + part;
    bool active = (d < n);
    int e0 = 0, deg = 0;
    if (active) {
        e0 = row_ptr[d];
        deg = degA[d];
    }
    int md = deg;
    md = max(md, __shfl_xor(md, 16));
    md = max(md, __shfl_xor(md, 32));

    float acc8[8] = {0, 0, 0, 0, 0, 0, 0, 0};
    gather4wide_scaled(zb, col_idx, dis, e0, deg, md, sl, part, active, acc8);

    unsigned outw[4] = {0, 0, 0, 0};
    if (active) {
        float dd = dis[d];
        uint4 v = *(const uint4*)(zb + ((size_t)d << 7) + (sl << 3));
        const unsigned* w = (const unsigned*)&v;
        #pragma unroll
        for (int i2 = 0; i2 < 4; ++i2) {
            float2 f = unpack_bf2(w[i2]);
            acc8[2 * i2]     = fmaf(f.x, dd, acc8[2 * i2]);
            acc8[2 * i2 + 1] = fmaf(f.y, dd, acc8[2 * i2 + 1]);
        }
        int f0 = sl << 3;
        #pragma unroll
        for (int i2 = 0; i2 < 4; ++i2) {
            int f = f0 + 2 * i2;
            float2 bv = *(const float2*)&bias[f];
            float2 gm = *(const float2*)&gamma[f];
            float2 bt = *(const float2*)&beta[f];
            float2 mn = *(const float2*)&mean[f];
            float2 vr = *(const float2*)&var[f];
            float vx = acc8[2 * i2] * dd + bv.x;
            float vy = acc8[2 * i2 + 1] * dd + bv.y;
            float sx = gm.x * rsqrtf(vr.x + BN_EPS);
            float sy = gm.y * rsqrtf(vr.y + BN_EPS);
            float rx = fmaxf((vx - mn.x) * sx + bt.x, 0.f);
            float ry = fmaxf((vy - mn.y) * sy + bt.y, 0.f);
            outw[i2] = pack_bf2(rx, ry);
        }
    }
    int local = wave * 4 + part;
    *(uint4*)&H1[local][sl << 3] = *(uint4*)outw;
    __syncthreads();

    // ---- GEMM2: hws2[16 rows] = dis * (H1 @ W2) ----
    int m = sl;
    int quad = part;
    short8 a2[4];
    #pragma unroll
    for (int kt = 0; kt < 4; ++kt)
        a2[kt] = *(const short8*)&H1[m][kt * 32 + quad * 8];

    f32x4 acc2[2];
    acc2[0] = (f32x4){0.f, 0.f, 0.f, 0.f};
    acc2[1] = (f32x4){0.f, 0.f, 0.f, 0.f};
    #pragma unroll
    for (int i = 0; i < 2; ++i) {
        int ct = wave * 2 + i;
        const unsigned short* wb = &wt2[(size_t)(ct * 16 + m) * 128 + quad * 8];
        #pragma unroll
        for (int kt = 0; kt < 4; ++kt) {
            short8 b = *(const short8*)(wb + kt * 32);
            acc2[i] = __builtin_amdgcn_mfma_f32_16x16x32_bf16(a2[kt], b, acc2[i], 0, 0, 0);
        }
    }
    int gr = blockIdx.x * 16 + quad * 4;
    float ds2[4];
    #pragma unroll
    for (int reg = 0; reg < 4; ++reg)
        ds2[reg] = (gr + reg < n) ? dis[gr + reg] : 0.f;
    #pragma unroll
    for (int i = 0; i < 2; ++i) {
        int col = (wave * 2 + i) * 16 + m;
        #pragma unroll
        for (int reg = 0; reg < 4; ++reg)
            C2[quad * 4 + reg][col] = bf16_1(acc2[i][reg] * ds2[reg]);
    }
    __syncthreads();
    {
        int r = t >> 4;
        int c8 = (t & 15) * 8;
        int grow = blockIdx.x * 16 + r;
        if (grow < n)
            *(uint4*)&hwsb2[(size_t)grow * 128 + c8] = *(const uint4*)&C2[r][c8];
    }
}

// ------- layer-2 agg + BN + ReLU + attention + logits; block=256, 16 nodes -------

__global__ __launch_bounds__(256) void k_agg2_att_logit(const unsigned short* __restrict__ hwsb,
                                                        const int* __restrict__ row_ptr,
                                                        const int* __restrict__ degA,
                                                        const int* __restrict__ col_idx,
                                                        const float* __restrict__ dis,
                                                        const float* __restrict__ bias,
                                                        const float* __restrict__ gamma,
                                                        const float* __restrict__ beta,
                                                        const float* __restrict__ mean,
                                                        const float* __restrict__ var,
                                                        const int* __restrict__ batch,
                                                        const float* __restrict__ att_w,
                                                        const float* __restrict__ cls_w,
                                                        float* __restrict__ att_out,
                                                        float* __restrict__ logits, int n) {
    __shared__ int   sg[16];
    __shared__ float sv[16];
    int t = threadIdx.x;
    int wave = t >> 6, lane = t & 63;
    int sl = lane & 15, part = lane >> 4;
    int d = blockIdx.x * 16 + wave * 4 + part;
    bool active = (d < n);
    int e0 = 0, deg = 0;
    if (active) {
        e0 = row_ptr[d];
        deg = degA[d];
    }
    int md = deg;
    md = max(md, __shfl_xor(md, 16));
    md = max(md, __shfl_xor(md, 32));

    float acc8[8] = {0, 0, 0, 0, 0, 0, 0, 0};
    gather4wide(hwsb, col_idx, e0, deg, md, sl, part, active, acc8);

    int g = -1;
    float contrib = 0.f;
    float p = 0.f, q = 0.f;
    if (active) {
        uint4 v = *(const uint4*)(hwsb + ((size_t)d << 7) + (sl << 3));
        const unsigned* w = (const unsigned*)&v;
        #pragma unroll
        for (int i2 = 0; i2 < 4; ++i2) {
            float2 f = unpack_bf2(w[i2]);
            acc8[2 * i2]     += f.x;
            acc8[2 * i2 + 1] += f.y;
        }
        float dd = dis[d];
        int f0 = sl << 3;
        #pragma unroll
        for (int i2 = 0; i2 < 4; ++i2) {
            int f = f0 + 2 * i2;
            float2 bv = *(const float2*)&bias[f];
            float2 gm = *(const float2*)&gamma[f];
            float2 bt = *(const float2*)&beta[f];
            float2 mn = *(const float2*)&mean[f];
            float2 vr = *(const float2*)&var[f];
            float vx = acc8[2 * i2] * dd + bv.x;
            float vy = acc8[2 * i2 + 1] * dd + bv.y;
            float sx = gm.x * rsqrtf(vr.x + BN_EPS);
            float sy = gm.y * rsqrtf(vr.y + BN_EPS);
            float rx = fmaxf((vx - mn.x) * sx + bt.x, 0.f);
            float ry = fmaxf((vy - mn.y) * sy + bt.y, 0.f);
            float2 aw = *(const float2*)&att_w[f];
            float2 cw = *(const float2*)&cls_w[f];
            p += rx * aw.x + ry * aw.y;
            q += rx * cw.x + ry * cw.y;
        }
    }
    #pragma unroll
    for (int off = 1; off < 16; off <<= 1) {
        p += __shfl_xor(p, off);
        q += __shfl_xor(q, off);
    }
    if (active) {
        float a = 1.f / (1.f + expf(-p));
        if (sl == 0) att_out[d] = a;
        g = batch[d];
        contrib = a * q;
    }
    if (sl == 0) {
        sg[wave * 4 + part] = g;
        sv[wave * 4 + part] = contrib;
    }
    __syncthreads();
    if (t == 0) {
        int cur = -1;
        float acc = 0.f;
        #pragma unroll
        for (int i = 0; i < 16; ++i) {
            int gi = sg[i];
            if (gi < 0) continue;
            if (gi != cur) {
                if (cur >= 0) atomicAdd(&logits[cur], acc);
                cur = gi;
                acc = 0.f;
            }
            acc += sv[i];
        }
        if (cur >= 0) atomicAdd(&logits[cur], acc);
    }
}

// ---------------- launch ----------------

extern "C" void kernel_launch(void* const* d_in, const int* in_sizes, int n_in,
                              void* d_out, int out_size, void* d_ws, size_t ws_size,
                              hipStream_t stream) {
    const float* x   = (const float*)d_in[0];
    const int*   ei  = (const int*)d_in[1];
    const int*   bat = (const int*)d_in[2];
    const float* W1  = (const float*)d_in[3];
    const float* b1  = (const float*)d_in[4];
    const float* g1  = (const float*)d_in[5];
    const float* bt1 = (const float*)d_in[6];
    const float* mn1 = (const float*)d_in[7];
    const float* vr1 = (const float*)d_in[8];
    const float* W2  = (const float*)d_in[9];
    const float* b2  = (const float*)d_in[10];
    const float* g2  = (const float*)d_in[11];
    const float* bt2 = (const float*)d_in[12];
    const float* mn2 = (const float*)d_in[13];
    const float* vr2 = (const float*)d_in[14];
    const float* attw = (const float*)d_in[15];
    const float* clsw = (const float*)d_in[16];
    const float* clsb = (const float*)d_in[17];

    int E = in_sizes[1] / 2;
    int n = in_sizes[2];
    const int* src = ei;
    const int* dst = ei + E;
    int K = (n + NBKT - 1) / NBKT;

    char* ws = (char*)d_ws;
    auto alloc = [&](size_t bytes) {
        void* p = (void*)ws;
        ws += (bytes + 255) & ~(size_t)255;
        return p;
    };
    int*            bcurP   = (int*)alloc(NBKT * 16 * 4);
    unsigned*       bpacked = (unsigned*)alloc((size_t)NBKT * CAP * 4);
    int*            row_ptr = (int*)alloc((size_t)n * 4);
    int*            degA    = (int*)alloc((size_t)n * 4);
    int*            col_idx = (int*)alloc((size_t)NBKT * CAP * 4);
    float*          dis     = (float*)alloc((size_t)n * 4);
    unsigned short* zb      = (unsigned short*)alloc((size_t)n * 128 * 2);  // z = x@W1 (unscaled)
    unsigned short* hwsb2   = (unsigned short*)alloc((size_t)n * 128 * 2);
    unsigned short* wt1     = (unsigned short*)alloc(128 * 128 * 2);
    unsigned short* wt2     = (unsigned short*)alloc(128 * 128 * 2);

    float* out = (float*)d_out;
    int etiles = (E + ETILE - 1) / ETILE;
    int gb = (n + 63) / 64;
    int ab = (n + 15) / 16;

    k_prep0<<<257, 128, 0, stream>>>(W1, W2, wt1, wt2, bcurP, clsb, out);
    k_distribute<<<etiles, 256, 0, stream>>>(src, dst, bcurP, bpacked, E, K);
    k_csr_gemm1<<<NBKT + gb, 256, 0, stream>>>(bpacked, bcurP, row_ptr, degA, dis,
                                               col_idx, x, wt1, zb, n, K);
    k_agg1_gemm2<<<ab, 256, 0, stream>>>(zb, row_ptr, degA, col_idx, dis,
                                         b1, g1, bt1, mn1, vr1, wt2, hwsb2, n);
    k_agg2_att_logit<<<ab, 256, 0, stream>>>(hwsb2, row_ptr, degA, col_idx, dis,
                                             b2, g2, bt2, mn2, vr2, bat, attw, clsw,
                                             out + NG, out, n);
}

// Round 17
// 280.091 us; speedup vs baseline: 1.1401x; 1.0269x over previous
//
#include <hip/hip_runtime.h>
#include <math.h>

#define NN 50000
#define HID 128
#define NG 64
#define BN_EPS 1e-5f

typedef __attribute__((ext_vector_type(8))) short short8;
typedef __attribute__((ext_vector_type(4))) float f32x4;

// ---- bf16 pack/unpack (RNE) ----
__device__ inline unsigned pack_bf2(float a, float b) {
    union { float f; unsigned u; } ua, ub;
    ua.f = a; ub.f = b;
    unsigned x = ua.u, y = ub.u;
    x += 0x7fffu + ((x >> 16) & 1u);
    y += 0x7fffu + ((y >> 16) & 1u);
    return (x >> 16) | (y & 0xffff0000u);
}
__device__ inline unsigned short bf16_1(float x) {
    union { float f; unsigned u; } v;
    v.f = x;
    unsigned r = v.u + 0x7fffu + ((v.u >> 16) & 1u);
    return (unsigned short)(r >> 16);
}
__device__ inline float2 unpack_bf2(unsigned v) {
    union { unsigned u; float f; } a, b;
    a.u = v << 16;
    b.u = v & 0xffff0000u;
    return make_float2(a.f, b.f);
}

// =============== CSR build — fixed-capacity buckets ===============
#define NBKT 256
#define ETILE 2048
#define EPT   (ETILE / 256)     // 8 edges per thread
#define CAP   8192
#define ASTR 136

// prep: blocks 0..255 W transpose+bf16; block 256 zero cursors + seed logits
__global__ __launch_bounds__(128) void k_prep0(const float* __restrict__ W1,
                                               const float* __restrict__ W2,
                                               unsigned short* __restrict__ wt1,
                                               unsigned short* __restrict__ wt2,
                                               int* __restrict__ bcurP,
                                               const float* __restrict__ cls_b,
                                               float* __restrict__ logits) {
    int b = blockIdx.x;
    int t = threadIdx.x;
    if (b < 256) {
        int k = b & 127;
        const float* W = (b < 128) ? W1 : W2;
        unsigned short* wt = (b < 128) ? wt1 : wt2;
        wt[t * 128 + k] = bf16_1(W[k * 128 + t]);
    } else {
        #pragma unroll
        for (int i = 0; i < 32; ++i) bcurP[t * 32 + i] = 0;
        if (t < NG) logits[t] = cls_b[0];
    }
}

// pure scatter of packed edges into bucket segments (relative cursors);
// dst cached in registers across the two passes.
__global__ __launch_bounds__(256) void k_distribute(const int* __restrict__ src,
                                                    const int* __restrict__ dst,
                                                    int* __restrict__ bcurP,
                                                    unsigned* __restrict__ bpacked,
                                                    int E, int K) {
    __shared__ int h[NBKT];
    int t = threadIdx.x;
    h[t] = 0;
    __syncthreads();
    int base = blockIdx.x * ETILE;
    int dreg[EPT];
    #pragma unroll
    for (int i = 0; i < EPT; ++i) {
        int e = base + i * 256 + t;
        dreg[i] = (e < E) ? dst[e] : -1;
        if (dreg[i] >= 0) atomicAdd(&h[dreg[i] / K], 1);
    }
    __syncthreads();
    int c = h[t];
    int my = (c > 0) ? atomicAdd(&bcurP[t * 16], c) : 0;
    __syncthreads();
    h[t] = my;
    __syncthreads();
    #pragma unroll
    for (int i = 0; i < EPT; ++i) {
        int e = base + i * 256 + t;
        if (dreg[i] >= 0) {
            int d = dreg[i];
            int bkt = d / K;
            int p = atomicAdd(&h[bkt], 1);
            bpacked[(size_t)bkt * CAP + p] = ((unsigned)d << 16) | (unsigned)src[e];
        }
    }
}

// blocks < NBKT: bucket CSR counting sort. blocks >= NBKT: gemm1 z = bf16(x@W1) UNSCALED
__global__ __launch_bounds__(256) void k_csr_gemm1(const unsigned* __restrict__ bpacked,
                                                   const int* __restrict__ bcurP,
                                                   int* __restrict__ row_ptr,
                                                   int* __restrict__ degA,
                                                   float* __restrict__ dis,
                                                   int* __restrict__ col_idx,
                                                   const float* __restrict__ x,
                                                   const unsigned short* __restrict__ wt1,
                                                   unsigned short* __restrict__ zb,
                                                   int n, int K) {
    __shared__ unsigned short A[64][ASTR];
    __shared__ int cnt[NBKT];
    __shared__ int sA[NBKT];
    __shared__ int cur[NBKT];
    int t = threadIdx.x;
    int b = blockIdx.x;

    if (b >= NBKT) {
        // ---------------- gemm1 path ----------------
        int row0 = (b - NBKT) * 64;
        #pragma unroll
        for (int i = 0; i < 8; ++i) {
            int idx = t + i * 256;
            int r = idx >> 5;
            int c4 = (idx & 31) * 4;
            float4 v = make_float4(0.f, 0.f, 0.f, 0.f);
            if (row0 + r < n) v = *(const float4*)&x[(size_t)(row0 + r) * 128 + c4];
            uint2 p;
            p.x = pack_bf2(v.x, v.y);
            p.y = pack_bf2(v.z, v.w);
            *(uint2*)&A[r][c4] = p;
        }
        __syncthreads();
        int lane = t & 63;
        int wave = t >> 6;
        int m = lane & 15;
        int quad = lane >> 4;
        int r0 = wave * 16;
        short8 a[4];
        #pragma unroll
        for (int kt = 0; kt < 4; ++kt)
            a[kt] = *(const short8*)&A[r0 + m][kt * 32 + quad * 8];
        f32x4 acc[8];
        #pragma unroll
        for (int ct = 0; ct < 8; ++ct) acc[ct] = (f32x4){0.f, 0.f, 0.f, 0.f};
        short8 bcur[4], bnxt[4];
        {
            const unsigned short* wb = &wt1[(size_t)m * 128 + quad * 8];
            #pragma unroll
            for (int kt = 0; kt < 4; ++kt) bcur[kt] = *(const short8*)(wb + kt * 32);
        }
        #pragma unroll
        for (int ct = 0; ct < 8; ++ct) {
            if (ct < 7) {
                const unsigned short* wb = &wt1[(size_t)((ct + 1) * 16 + m) * 128 + quad * 8];
                #pragma unroll
                for (int kt = 0; kt < 4; ++kt) bnxt[kt] = *(const short8*)(wb + kt * 32);
            }
            #pragma unroll
            for (int kt = 0; kt < 4; ++kt)
                acc[ct] = __builtin_amdgcn_mfma_f32_16x16x32_bf16(a[kt], bcur[kt], acc[ct], 0, 0, 0);
            #pragma unroll
            for (int kt = 0; kt < 4; ++kt) bcur[kt] = bnxt[kt];
        }
        __syncthreads();
        #pragma unroll
        for (int ct = 0; ct < 8; ++ct) {
            int col = ct * 16 + m;
            #pragma unroll
            for (int reg = 0; reg < 4; ++reg)
                A[r0 + quad * 4 + reg][col] = bf16_1(acc[ct][reg]);
        }
        __syncthreads();
        #pragma unroll
        for (int i = 0; i < 4; ++i) {
            int idx = t + i * 256;
            int r = idx >> 4;
            int c8 = (idx & 15) * 8;
            int grow = row0 + r;
            if (grow < n)
                *(uint4*)&zb[(size_t)grow * 128 + c8] = *(const uint4*)&A[r][c8];
        }
        return;
    }

    // ---------------- bucket CSR path ----------------
    int node0 = b * K;
    int nn = n - node0;
    if (nn > K) nn = K;
    if (nn < 0) nn = 0;
    int e0 = b * CAP;
    int e1 = e0 + bcurP[b * 16];
    cnt[t] = 0;
    __syncthreads();
    for (int e = e0 + t; e < e1; e += 256) {
        int ld = (int)(bpacked[e] >> 16) - node0;
        atomicAdd(&cnt[ld], 1);
    }
    __syncthreads();
    int c = cnt[t];
    sA[t] = c;
    __syncthreads();
    for (int off = 1; off < NBKT; off <<= 1) {
        int v = (t >= off) ? sA[t - off] : 0;
        __syncthreads();
        sA[t] += v;
        __syncthreads();
    }
    int rp = e0 + sA[t] - c;
    cur[t] = rp;
    if (t < nn) {
        row_ptr[node0 + t] = rp;
        degA[node0 + t] = c;
        dis[node0 + t] = rsqrtf((float)(c + 1));
    }
    __syncthreads();
    for (int e = e0 + t; e < e1; e += 256) {
        unsigned v = bpacked[e];
        int ld = (int)(v >> 16) - node0;
        int p = atomicAdd(&cur[ld], 1);
        col_idx[p] = (int)(v & 0xFFFFu);
    }
}

// =============== agg cores: 16 lanes/node, 16 uint4 in flight ===============

__device__ inline void gather4wide(const unsigned short* __restrict__ hwsb,
                                   const int* __restrict__ col_idx,
                                   int e0, int deg, int md,
                                   int sl, int part, bool active,
                                   float* acc8) {
    int cidx = (active && sl < deg) ? col_idx[e0 + sl] : 0;
    for (int it0 = 0; it0 < md; it0 += 16) {
        int nx = it0 + 16;
        int cidx_next = (active && (nx + sl) < deg && nx < md) ? col_idx[e0 + nx + sl] : 0;
        uint4 vv[16];
        #pragma unroll
        for (int j = 0; j < 16; ++j) {
            int s = __shfl(cidx, (part << 4) + j);
            vv[j] = (it0 + j < deg)
                        ? *(const uint4*)(hwsb + ((size_t)s << 7) + (sl << 3))
                        : make_uint4(0, 0, 0, 0);
        }
        #pragma unroll
        for (int j = 0; j < 16; ++j) {
            const unsigned* w = (const unsigned*)&vv[j];
            #pragma unroll
            for (int i2 = 0; i2 < 4; ++i2) {
                float2 f = unpack_bf2(w[i2]);
                acc8[2 * i2]     += f.x;
                acc8[2 * i2 + 1] += f.y;
            }
        }
        cidx = cidx_next;
    }
}

__device__ inline void gather4wide_scaled(const unsigned short* __restrict__ zb,
                                          const int* __restrict__ col_idx,
                                          const float* __restrict__ dis,
                                          int e0, int deg, int md,
                                          int sl, int part, bool active,
                                          float* acc8) {
    int cidx = (active && sl < deg) ? col_idx[e0 + sl] : 0;
    float cdis = (active && sl < deg) ? dis[cidx] : 0.f;
    for (int it0 = 0; it0 < md; it0 += 16) {
        int nx = it0 + 16;
        bool okn = (active && (nx + sl) < deg && nx < md);
        int cidx_next = okn ? col_idx[e0 + nx + sl] : 0;
        float cdis_next = okn ? dis[cidx_next] : 0.f;
        uint4 vv[16];
        float dsj[16];
        #pragma unroll
        for (int j = 0; j < 16; ++j) {
            int s = __shfl(cidx, (part << 4) + j);
            dsj[j] = __shfl(cdis, (part << 4) + j);
            vv[j] = (it0 + j < deg)
                        ? *(const uint4*)(zb + ((size_t)s << 7) + (sl << 3))
                        : make_uint4(0, 0, 0, 0);
        }
        #pragma unroll
        for (int j = 0; j < 16; ++j) {
            const unsigned* w = (const unsigned*)&vv[j];
            #pragma unroll
            for (int i2 = 0; i2 < 4; ++i2) {
                float2 f = unpack_bf2(w[i2]);
                acc8[2 * i2]     = fmaf(f.x, dsj[j], acc8[2 * i2]);
                acc8[2 * i2 + 1] = fmaf(f.y, dsj[j], acc8[2 * i2 + 1]);
            }
        }
        cidx = cidx_next;
        cdis = cdis_next;
    }
}

// ------- FUSED: layer-1 agg (scaled gather) + BN + ReLU -> h1 (LDS) -> GEMM2 -> hws2 -------

__global__ __launch_bounds__(256) void k_agg1_gemm2(const unsigned short* __restrict__ zb,
                                                    const int* __restrict__ row_ptr,
                                                    const int* __restrict__ degA,
                                                    const int* __restrict__ col_idx,
                                                    const float* __restrict__ dis,
                                                    const float* __restrict__ bias,
                                                    const float* __restrict__ gamma,
                                                    const float* __restrict__ beta,
                                                    const float* __restrict__ mean,
                                                    const float* __restrict__ var,
                                                    const unsigned short* __restrict__ wt2,
                                                    unsigned short* __restrict__ hwsb2, int n) {
    __shared__ unsigned short H1[16][ASTR];
    __shared__ unsigned short C2[16][ASTR];
    int t = threadIdx.x;
    int wave = t >> 6, lane = t & 63;
    int sl = lane & 15, part = lane >> 4;
    int d = blockIdx.x * 16 + wave * 4 + part;
    bool active = (d < n);
    int e0 = 0, deg = 0;
    if (active) {
        e0 = row_ptr[d];
        deg = degA[d];
    }
    int md = deg;
    md = max(md, __shfl_xor(md, 16));
    md = max(md, __shfl_xor(md, 32));

    float acc8[8] = {0, 0, 0, 0, 0, 0, 0, 0};
    gather4wide_scaled(zb, col_idx, dis, e0, deg, md, sl, part, active, acc8);

    unsigned outw[4] = {0, 0, 0, 0};
    if (active) {
        float dd = dis[d];
        uint4 v = *(const uint4*)(zb + ((size_t)d << 7) + (sl << 3));
        const unsigned* w = (const unsigned*)&v;
        #pragma unroll
        for (int i2 = 0; i2 < 4; ++i2) {
            float2 f = unpack_bf2(w[i2]);
            acc8[2 * i2]     = fmaf(f.x, dd, acc8[2 * i2]);
            acc8[2 * i2 + 1] = fmaf(f.y, dd, acc8[2 * i2 + 1]);
        }
        int f0 = sl << 3;
        #pragma unroll
        for (int i2 = 0; i2 < 4; ++i2) {
            int f = f0 + 2 * i2;
            float2 bv = *(const float2*)&bias[f];
            float2 gm = *(const float2*)&gamma[f];
            float2 bt = *(const float2*)&beta[f];
            float2 mn = *(const float2*)&mean[f];
            float2 vr = *(const float2*)&var[f];
            float vx = acc8[2 * i2] * dd + bv.x;
            float vy = acc8[2 * i2 + 1] * dd + bv.y;
            float sx = gm.x * rsqrtf(vr.x + BN_EPS);
            float sy = gm.y * rsqrtf(vr.y + BN_EPS);
            float rx = fmaxf((vx - mn.x) * sx + bt.x, 0.f);
            float ry = fmaxf((vy - mn.y) * sy + bt.y, 0.f);
            outw[i2] = pack_bf2(rx, ry);
        }
    }
    int local = wave * 4 + part;
    *(uint4*)&H1[local][sl << 3] = *(uint4*)outw;
    __syncthreads();

    int m = sl;
    int quad = part;
    short8 a2[4];
    #pragma unroll
    for (int kt = 0; kt < 4; ++kt)
        a2[kt] = *(const short8*)&H1[m][kt * 32 + quad * 8];

    f32x4 acc2[2];
    acc2[0] = (f32x4){0.f, 0.f, 0.f, 0.f};
    acc2[1] = (f32x4){0.f, 0.f, 0.f, 0.f};
    #pragma unroll
    for (int i = 0; i < 2; ++i) {
        int ct = wave * 2 + i;
        const unsigned short* wb = &wt2[(size_t)(ct * 16 + m) * 128 + quad * 8];
        #pragma unroll
        for (int kt = 0; kt < 4; ++kt) {
            short8 b = *(const short8*)(wb + kt * 32);
            acc2[i] = __builtin_amdgcn_mfma_f32_16x16x32_bf16(a2[kt], b, acc2[i], 0, 0, 0);
        }
    }
    int gr = blockIdx.x * 16 + quad * 4;
    float ds2[4];
    #pragma unroll
    for (int reg = 0; reg < 4; ++reg)
        ds2[reg] = (gr + reg < n) ? dis[gr + reg] : 0.f;
    #pragma unroll
    for (int i = 0; i < 2; ++i) {
        int col = (wave * 2 + i) * 16 + m;
        #pragma unroll
        for (int reg = 0; reg < 4; ++reg)
            C2[quad * 4 + reg][col] = bf16_1(acc2[i][reg] * ds2[reg]);
    }
    __syncthreads();
    {
        int r = t >> 4;
        int c8 = (t & 15) * 8;
        int grow = blockIdx.x * 16 + r;
        if (grow < n)
            *(uint4*)&hwsb2[(size_t)grow * 128 + c8] = *(const uint4*)&C2[r][c8];
    }
}

// ------- layer-2 agg + BN + ReLU + attention + logits; block=256, 16 nodes -------

__global__ __launch_bounds__(256) void k_agg2_att_logit(const unsigned short* __restrict__ hwsb,
                                                        const int* __restrict__ row_ptr,
                                                        const int* __restrict__ degA,
                                                        const int* __restrict__ col_idx,
                                                        const float* __restrict__ dis,
                                                        const float* __restrict__ bias,
                                                        const float* __restrict__ gamma,
                                                        const float* __restrict__ beta,
                                                        const float* __restrict__ mean,
                                                        const float* __restrict__ var,
                                                        const int* __restrict__ batch,
                                                        const float* __restrict__ att_w,
                                                        const float* __restrict__ cls_w,
                                                        float* __restrict__ att_out,
                                                        float* __restrict__ logits, int n) {
    __shared__ int   sg[16];
    __shared__ float sv[16];
    int t = threadIdx.x;
    int wave = t >> 6, lane = t & 63;
    int sl = lane & 15, part = lane >> 4;
    int d = blockIdx.x * 16 + wave * 4 + part;
    bool active = (d < n);
    int e0 = 0, deg = 0;
    if (active) {
        e0 = row_ptr[d];
        deg = degA[d];
    }
    int md = deg;
    md = max(md, __shfl_xor(md, 16));
    md = max(md, __shfl_xor(md, 32));

    float acc8[8] = {0, 0, 0, 0, 0, 0, 0, 0};
    gather4wide(hwsb, col_idx, e0, deg, md, sl, part, active, acc8);

    int g = -1;
    float contrib = 0.f;
    float p = 0.f, q = 0.f;
    if (active) {
        uint4 v = *(const uint4*)(hwsb + ((size_t)d << 7) + (sl << 3));
        const unsigned* w = (const unsigned*)&v;
        #pragma unroll
        for (int i2 = 0; i2 < 4; ++i2) {
            float2 f = unpack_bf2(w[i2]);
            acc8[2 * i2]     += f.x;
            acc8[2 * i2 + 1] += f.y;
        }
        float dd = dis[d];
        int f0 = sl << 3;
        #pragma unroll
        for (int i2 = 0; i2 < 4; ++i2) {
            int f = f0 + 2 * i2;
            float2 bv = *(const float2*)&bias[f];
            float2 gm = *(const float2*)&gamma[f];
            float2 bt = *(const float2*)&beta[f];
            float2 mn = *(const float2*)&mean[f];
            float2 vr = *(const float2*)&var[f];
            float vx = acc8[2 * i2] * dd + bv.x;
            float vy = acc8[2 * i2 + 1] * dd + bv.y;
            float sx = gm.x * rsqrtf(vr.x + BN_EPS);
            float sy = gm.y * rsqrtf(vr.y + BN_EPS);
            float rx = fmaxf((vx - mn.x) * sx + bt.x, 0.f);
            float ry = fmaxf((vy - mn.y) * sy + bt.y, 0.f);
            float2 aw = *(const float2*)&att_w[f];
            float2 cw = *(const float2*)&cls_w[f];
            p += rx * aw.x + ry * aw.y;
            q += rx * cw.x + ry * cw.y;
        }
    }
    #pragma unroll
    for (int off = 1; off < 16; off <<= 1) {
        p += __shfl_xor(p, off);
        q += __shfl_xor(q, off);
    }
    if (active) {
        float a = 1.f / (1.f + expf(-p));
        if (sl == 0) att_out[d] = a;
        g = batch[d];
        contrib = a * q;
    }
    if (sl == 0) {
        sg[wave * 4 + part] = g;
        sv[wave * 4 + part] = contrib;
    }
    __syncthreads();
    if (t == 0) {
        int cur = -1;
        float acc = 0.f;
        #pragma unroll
        for (int i = 0; i < 16; ++i) {
            int gi = sg[i];
            if (gi < 0) continue;
            if (gi != cur) {
                if (cur >= 0) atomicAdd(&logits[cur], acc);
                cur = gi;
                acc = 0.f;
            }
            acc += sv[i];
        }
        if (cur >= 0) atomicAdd(&logits[cur], acc);
    }
}

// ---------------- launch ----------------

extern "C" void kernel_launch(void* const* d_in, const int* in_sizes, int n_in,
                              void* d_out, int out_size, void* d_ws, size_t ws_size,
                              hipStream_t stream) {
    const float* x   = (const float*)d_in[0];
    const int*   ei  = (const int*)d_in[1];
    const int*   bat = (const int*)d_in[2];
    const float* W1  = (const float*)d_in[3];
    const float* b1  = (const float*)d_in[4];
    const float* g1  = (const float*)d_in[5];
    const float* bt1 = (const float*)d_in[6];
    const float* mn1 = (const float*)d_in[7];
    const float* vr1 = (const float*)d_in[8];
    const float* W2  = (const float*)d_in[9];
    const float* b2  = (const float*)d_in[10];
    const float* g2  = (const float*)d_in[11];
    const float* bt2 = (const float*)d_in[12];
    const float* mn2 = (const float*)d_in[13];
    const float* vr2 = (const float*)d_in[14];
    const float* attw = (const float*)d_in[15];
    const float* clsw = (const float*)d_in[16];
    const float* clsb = (const float*)d_in[17];

    int E = in_sizes[1] / 2;
    int n = in_sizes[2];
    const int* src = ei;
    const int* dst = ei + E;
    int K = (n + NBKT - 1) / NBKT;

    char* ws = (char*)d_ws;
    auto alloc = [&](size_t bytes) {
        void* p = (void*)ws;
        ws += (bytes + 255) & ~(size_t)255;
        return p;
    };
    int*            bcurP   = (int*)alloc(NBKT * 16 * 4);
    unsigned*       bpacked = (unsigned*)alloc((size_t)NBKT * CAP * 4);
    int*            row_ptr = (int*)alloc((size_t)n * 4);
    int*            degA    = (int*)alloc((size_t)n * 4);
    int*            col_idx = (int*)alloc((size_t)NBKT * CAP * 4);
    float*          dis     = (float*)alloc((size_t)n * 4);
    unsigned short* zb      = (unsigned short*)alloc((size_t)n * 128 * 2);
    unsigned short* hwsb2   = (unsigned short*)alloc((size_t)n * 128 * 2);
    unsigned short* wt1     = (unsigned short*)alloc(128 * 128 * 2);
    unsigned short* wt2     = (unsigned short*)alloc(128 * 128 * 2);

    float* out = (float*)d_out;
    int etiles = (E + ETILE - 1) / ETILE;
    int gb = (n + 63) / 64;
    int ab = (n + 15) / 16;

    k_prep0<<<257, 128, 0, stream>>>(W1, W2, wt1, wt2, bcurP, clsb, out);
    k_distribute<<<etiles, 256, 0, stream>>>(src, dst, bcurP, bpacked, E, K);
    k_csr_gemm1<<<NBKT + gb, 256, 0, stream>>>(bpacked, bcurP, row_ptr, degA, dis,
                                               col_idx, x, wt1, zb, n, K);
    k_agg1_gemm2<<<ab, 256, 0, stream>>>(zb, row_ptr, degA, col_idx, dis,
                                         b1, g1, bt1, mn1, vr1, wt2, hwsb2, n);
    k_agg2_att_logit<<<ab, 256, 0, stream>>>(hwsb2, row_ptr, degA, col_idx, dis,
                                             b2, g2, bt2, mn2, vr2, bat, attw, clsw,
                                             out + NG, out, n);
}